// Round 1
// 2639.945 us; speedup vs baseline: 1.6014x; 1.6014x over previous
//
#include <hip/hip_runtime.h>
#include <math.h>

typedef unsigned short u16;
typedef unsigned int   u32;

#define HDIM 96
#define SDIM 48
#define FDIM 24
#define KA   312      // 2H + 2S + F
#define WATT 192
#define KG   288      // 3H

// edge MFMA tiling
#define AS_E  328     // edge A LDS row stride in u16 (656 B, 16B-aligned)
#define KT_A  10      // K-steps of 32 (K padded 312 -> 320)
#define KT_G  9       // node K-steps (288)

#define NFRAG (2 * KT_A * 12 * 64)   // #16B fragments in prepped W1 (both mlps)

typedef __attribute__((ext_vector_type(8))) __bf16 bf16x8;
typedef __attribute__((ext_vector_type(4))) float  f32x4;

__device__ __forceinline__ u16 f2bf(float f) {
  u32 u = __float_as_uint(f);
  u = (u + 0x7FFFu + ((u >> 16) & 1u)) >> 16;   // RNE
  return (u16)u;
}
__device__ __forceinline__ u32 pack2(float a, float b) {
  return (u32)f2bf(a) | ((u32)f2bf(b) << 16);
}
__device__ __forceinline__ f32x4 mfma_bf16(bf16x8 a, bf16x8 b, f32x4 c) {
  return __builtin_amdgcn_mfma_f32_16x16x32_bf16(a, b, c, 0, 0, 0);
}

// ===========================================================================
// Weight prep: convert fwd/rev W1 (fp32, [192 x 312]) to bf16 MFMA fragments
// in workspace, once per launch. Fragment (mlp, kt, nt, lane(q,c)) holds
// W1bf[n = nt*16+c][k = kt*32 + q*8 .. +8] (16 B). rev input-permutation
// (fp32-pair sigma: [0,48)<->[48,96), [96,120)<->[120,144)) folded in here.
// K padded 312 -> 320 with zeros. 15360 threads total; negligible cost.
// ===========================================================================
__global__ __launch_bounds__(256) void w_prep(
    const float* __restrict__ fW1, const float* __restrict__ rW1,
    u32* __restrict__ Bfrag)
{
  const int idx = blockIdx.x * 256 + threadIdx.x;
  if (idx >= NFRAG) return;
  const int lane = idx & 63;
  const int frag = idx >> 6;
  const int nt   = frag % 12;
  const int rest = frag / 12;
  const int kt   = rest % KT_A;
  const int mlp  = rest / KT_A;
  const int q = lane >> 4, c = lane & 15;
  const int n  = nt * 16 + c;
  const int p0 = kt * 16 + q * 4;            // first fp32-pair index
  const float* W = mlp ? rW1 : fW1;
  u32 v[4];
#pragma unroll
  for (int w = 0; w < 4; ++w) {
    const int p = p0 + w;
    u32 val = 0u;
    if (p < 156) {
      int src = p;
      if (mlp) {                             // sigma (pair units)
        if (src < 48)       src += 48;
        else if (src < 96)  src -= 48;
        else if (src < 120) src += 24;
        else if (src < 144) src -= 24;
      }
      const float2 wv = *(const float2*)(W + (size_t)n * KA + 2 * src);
      val = pack2(wv.x, wv.y);
    }
    v[w] = val;
  }
  ((uint4*)Bfrag)[idx] = make_uint4(v[0], v[1], v[2], v[3]);
}

// ===========================================================================
// Edge kernel (MFMA): 64 edges/block, 256 threads (4 waves).
// A = feat [64 x 320] bf16 in LDS. W1 fragments are PRE-CONVERTED (w_prep)
// and held in REGISTERS (30 bf16x8/wave/mlp, coalesced dwordx4 loads from
// L2) -> the K-loop is barrier-free: 4 ds_read_b128 + 12 MFMA per step.
// No Blds, no per-step staging, no per-step __syncthreads.
// Epilogue fuses bias+relu+dot(W2)+b2 -> softmax-exp (fwd: pe + denom
// atomic) / sigmoid (rev: fp32 out chunk 2).
// ===========================================================================
__global__ __launch_bounds__(256, 2) void edge_kernel(
    const float* __restrict__ x, const float* __restrict__ xs,
    const float* __restrict__ ef, const int* __restrict__ ei,
    const u16* __restrict__ Bfrag,
    const float* __restrict__ fb1, const float* __restrict__ fW2,
    const float* __restrict__ fb2,
    const float* __restrict__ rb1, const float* __restrict__ rW2,
    const float* __restrict__ rb2,
    float* __restrict__ pe, float* __restrict__ denom,
    float* __restrict__ out_revw, int N, int E)
{
  __shared__ __align__(16) u16 Alds[64 * AS_E];   // 41,984 B
  __shared__ float red[4][64];                    //  1,024 B

  const int tid  = threadIdx.x;
  const int wave = tid >> 6, lane = tid & 63;
  const int q = lane >> 4, c = lane & 15;
  const int e0 = blockIdx.x * 64;

  // ---- gather A as bf16 pairs (pair index p in [0,160), pad >=156 zero) ---
  {
    u32* Aw = (u32*)Alds;
    const int el = tid >> 2, sub = tid & 3;
    const int e = min(e0 + el, E - 1);
    int s = ei[e], d = ei[(size_t)E + e];
    s = min(max(s, 0), N - 1); d = min(max(d, 0), N - 1);
    for (int p = sub; p < 160; p += 4) {
      const int j = 2 * p;                        // fp32 element index
      float2 v = make_float2(0.f, 0.f);
      if (j < 96)       v = *(const float2*)(x  + (size_t)s * 96 + j);
      else if (j < 192) v = *(const float2*)(x  + (size_t)d * 96 + (j - 96));
      else if (j < 240) v = *(const float2*)(xs + (size_t)s * 48 + (j - 192));
      else if (j < 288) v = *(const float2*)(xs + (size_t)d * 48 + (j - 240));
      else if (j < 312) v = *(const float2*)(ef + (size_t)e * 24 + (j - 288));
      Aw[el * (AS_E / 2) + p] = pack2(v.x, v.y);
    }
  }
  __syncthreads();                                // A ready (read-only after)

  const bf16x8* __restrict__ Bf = (const bf16x8*)Bfrag;

  for (int mlp = 0; mlp < 2; ++mlp) {
    f32x4 acc[4][3];
#pragma unroll
    for (int m = 0; m < 4; ++m)
      for (int t = 0; t < 3; ++t)
        acc[m][t] = (f32x4){0.f, 0.f, 0.f, 0.f};

#pragma unroll
    for (int kt = 0; kt < KT_A; ++kt) {
      bf16x8 a[4];
#pragma unroll
      for (int m = 0; m < 4; ++m)
        a[m] = *(const bf16x8*)&Alds[(m * 16 + c) * AS_E + kt * 32 + q * 8];
#pragma unroll
      for (int t = 0; t < 3; ++t) {
        const bf16x8 b =
            Bf[(((mlp * KT_A + kt) * 12) + wave * 3 + t) * 64 + lane];
#pragma unroll
        for (int m = 0; m < 4; ++m)
          acc[m][t] = mfma_bf16(a[m], b, acc[m][t]);
      }
    }

    // ---- epilogue: bias + relu + dot(W2), reduce across 16 col-lanes ----
    const float* b1p = mlp ? rb1 : fb1;
    const float* W2p = mlp ? rW2 : fW2;
    float p[4][4];
#pragma unroll
    for (int m = 0; m < 4; ++m)
      for (int r = 0; r < 4; ++r) p[m][r] = 0.f;
#pragma unroll
    for (int t = 0; t < 3; ++t) {
      const int n = (wave * 3 + t) * 16 + c;
      const float b1f = b1p[n];
      const float w2f = W2p[n];
#pragma unroll
      for (int m = 0; m < 4; ++m)
        for (int r = 0; r < 4; ++r) {
          float h = acc[m][t][r] + b1f;
          h = h > 0.f ? h : 0.f;
          p[m][r] += h * w2f;
        }
    }
    for (int off = 1; off <= 8; off <<= 1)
#pragma unroll
      for (int m = 0; m < 4; ++m)
        for (int r = 0; r < 4; ++r)
          p[m][r] += __shfl_xor(p[m][r], off, 64);

    __syncthreads();                    // red safe to overwrite
    if (c == 0) {
#pragma unroll
      for (int m = 0; m < 4; ++m)
        for (int r = 0; r < 4; ++r)
          red[wave][m * 16 + q * 4 + r] = p[m][r];
    }
    __syncthreads();

    if (tid < 64 && e0 + tid < E) {
      float raw = red[0][tid] + red[1][tid] + red[2][tid] + red[3][tid];
      const int e = e0 + tid;
      if (mlp == 0) {
        raw += fb2[0];
        const float lr = raw > 0.f ? raw : 0.01f * raw;      // leaky_relu
        const float pv = __expf(lr * 0.10206207261596575f);  // /sqrt(96)
        pe[e] = pv;
        const int d = min(max(ei[(size_t)E + e], 0), N - 1);
        unsafeAtomicAdd(&denom[d], pv);
      } else {
        raw += rb2[0];
        out_revw[e] = 1.f / (1.f + __expf(-raw));
      }
    }
  }
}

// ===========================================================================
// Normalize + scatter-aggregate (unchanged).
// ===========================================================================
__global__ __launch_bounds__(256) void t_agg(
    const float* __restrict__ x, const int* __restrict__ ei,
    const float* __restrict__ pe, const float* __restrict__ out_revw,
    const float* __restrict__ denom,
    float* __restrict__ fwdm, float* __restrict__ revm,
    float* __restrict__ out_fwdw, int N, int E)
{
  const long long g = (long long)blockIdx.x * 256 + threadIdx.x;
  const int e = (int)(g / 48);
  if (e >= E) return;
  const int c2 = (int)(g - (long long)e * 48);
  const int s = min(max(ei[e], 0), N - 1);
  const int d = min(max(ei[(size_t)E + e], 0), N - 1);
  const float w = pe[e] / (denom[d] + 1e-9f);
  if (c2 == 0) out_fwdw[e] = w;
  const float rw = out_revw[e];
  const float2 xs2 = *(const float2*)(x + (size_t)s * 96 + 2 * c2);
  const float2 xd2 = *(const float2*)(x + (size_t)d * 96 + 2 * c2);
  unsafeAtomicAdd(&fwdm[(size_t)d * 96 + 2 * c2],     xs2.x * w);
  unsafeAtomicAdd(&fwdm[(size_t)d * 96 + 2 * c2 + 1], xs2.y * w);
  unsafeAtomicAdd(&revm[(size_t)s * 96 + 2 * c2],     xd2.x * rw);
  unsafeAtomicAdd(&revm[(size_t)s * 96 + 2 * c2 + 1], xd2.y * rw);
}

// ===========================================================================
// Node MLP (MFMA): 32 nodes/block, 256 threads. A = [x | fwdm | revm] bf16
// (MODE 2: first 96 cols are r*x, r read fp32 from out_r).
// layer1 288->288 -> relu -> Hlds (bf16), layer2 288->96.
// Epilogue: MODE 0 -> sigmoid -> out_r; MODE 1 -> sigmoid -> out_z;
// MODE 2 -> tanh + GRU gate (z from out_z fp32) -> out_update.
// ===========================================================================
template <int MODE>
__global__ __launch_bounds__(256) void node_kernel(
    const float* __restrict__ x,
    const float* __restrict__ fwdm, const float* __restrict__ revm,
    const float* __restrict__ W1, const float* __restrict__ b1,
    const float* __restrict__ W2, const float* __restrict__ b2,
    const float* __restrict__ rin, const float* __restrict__ zin,
    float* __restrict__ fout, int N)
{
  __shared__ __align__(16) u16 Alds[32 * KG];   // 18,432 B
  __shared__ __align__(16) u16 Hlds[32 * KG];   // 18,432 B
  __shared__ __align__(16) u16 Blds[KG * 32];   // 18,432 B (reused for W2)

  const int tid = threadIdx.x;
  const int wave = tid >> 6, lane = tid & 63;
  const int q = lane >> 4, c = lane & 15;
  const int n0 = blockIdx.x * 32;

  // ---- gather A (144 fp32-pairs per node row) ----
  {
    u32* Aw = (u32*)Alds;
    const int nl = tid >> 3, sub = tid & 7;
    const int node = min(n0 + nl, N - 1);
    for (int p = sub; p < 144; p += 8) {
      const int j = 2 * p;
      float2 v;
      if (j < 96) {
        v = *(const float2*)(x + (size_t)node * 96 + j);
        if (MODE == 2) {
          const float2 r2 = *(const float2*)(rin + (size_t)node * 96 + j);
          v.x *= r2.x; v.y *= r2.y;
        }
      } else if (j < 192) {
        v = *(const float2*)(fwdm + (size_t)node * 96 + (j - 96));
      } else {
        v = *(const float2*)(revm + (size_t)node * 96 + (j - 192));
      }
      Aw[nl * (KG / 2) + p] = pack2(v.x, v.y);
    }
  }

  // ---- layer 1: 288 -> 288 ----
  const int ntc = (wave < 2) ? 5 : 4;           // 18 N-tiles over 4 waves
  f32x4 acc[2][5];
  for (int m = 0; m < 2; ++m)
    for (int t = 0; t < 5; ++t) acc[m][t] = (f32x4){0.f, 0.f, 0.f, 0.f};
  for (int kt = 0; kt < KT_G; ++kt) {
    __syncthreads();
    u32* Bw = (u32*)Blds;
    for (int j = tid; j < KG * 16; j += 256) {
      const int n = j >> 4, kk = j & 15;
      const float2 w = *(const float2*)(W1 + (size_t)n * KG + kt * 32 + kk * 2);
      Bw[j] = pack2(w.x, w.y);
    }
    __syncthreads();
    const bf16x8 a0 = *(const bf16x8*)&Alds[c * KG + kt * 32 + q * 8];
    const bf16x8 a1 = *(const bf16x8*)&Alds[(16 + c) * KG + kt * 32 + q * 8];
    for (int t = 0; t < ntc; ++t) {
      const int nt = wave + 4 * t;
      const bf16x8 b = *(const bf16x8*)&Blds[(nt * 16 + c) * 32 + q * 8];
      acc[0][t] = mfma_bf16(a0, b, acc[0][t]);
      acc[1][t] = mfma_bf16(a1, b, acc[1][t]);
    }
  }
  // bias + relu -> Hlds (bf16)
  for (int t = 0; t < ntc; ++t) {
    const int n = (wave + 4 * t) * 16 + c;
    const float b1f = b1[n];
    for (int m = 0; m < 2; ++m)
      for (int r = 0; r < 4; ++r) {
        float h = acc[m][t][r] + b1f;
        h = h > 0.f ? h : 0.f;
        Hlds[(m * 16 + q * 4 + r) * KG + n] = f2bf(h);
      }
  }

  // ---- layer 2: 288 -> 96 ----
  const int ntc2 = (wave < 2) ? 2 : 1;          // 6 N-tiles over 4 waves
  f32x4 acc2[2][2];
  for (int m = 0; m < 2; ++m)
    for (int t = 0; t < 2; ++t) acc2[m][t] = (f32x4){0.f, 0.f, 0.f, 0.f};
  for (int kt = 0; kt < KT_G; ++kt) {
    __syncthreads();                            // guards Hlds completion (kt==0)
    u32* Bw = (u32*)Blds;
    for (int j = tid; j < HDIM * 16; j += 256) {
      const int n = j >> 4, kk = j & 15;
      const float2 w = *(const float2*)(W2 + (size_t)n * KG + kt * 32 + kk * 2);
      Bw[j] = pack2(w.x, w.y);
    }
    __syncthreads();
    const bf16x8 a0 = *(const bf16x8*)&Hlds[c * KG + kt * 32 + q * 8];
    const bf16x8 a1 = *(const bf16x8*)&Hlds[(16 + c) * KG + kt * 32 + q * 8];
    for (int t = 0; t < ntc2; ++t) {
      const int nt = wave + 4 * t;
      const bf16x8 b = *(const bf16x8*)&Blds[(nt * 16 + c) * 32 + q * 8];
      acc2[0][t] = mfma_bf16(a0, b, acc2[0][t]);
      acc2[1][t] = mfma_bf16(a1, b, acc2[1][t]);
    }
  }

  // ---- epilogue ----
  for (int t = 0; t < ntc2; ++t) {
    const int n2 = (wave + 4 * t) * 16 + c;
    const float b2f = b2[n2];
    for (int m = 0; m < 2; ++m)
      for (int r = 0; r < 4; ++r) {
        const int row = m * 16 + q * 4 + r;
        const int node = n0 + row;
        if (node < N) {
          const float v = acc2[m][t][r] + b2f;
          if (MODE < 2) {
            fout[(size_t)node * HDIM + n2] = 1.f / (1.f + __expf(-v));
          } else {
            const float ct = tanhf(v);
            const float z = zin[(size_t)node * HDIM + n2];
            const float xv = x[(size_t)node * HDIM + n2];
            fout[(size_t)node * HDIM + n2] = (1.f - z) * xv + z * ct;
          }
        }
      }
  }
}

__global__ void sentinel_kernel(float* out, int n, float val) {
  const int i = blockIdx.x * 256 + threadIdx.x;
  if (i < n) out[i] = val;
}

// ---------------------------------------------------------------------------
extern "C" void kernel_launch(void* const* d_in, const int* in_sizes, int n_in,
                              void* d_out, int out_size, void* d_ws, size_t ws_size,
                              hipStream_t stream) {
  const float* x  = (const float*)d_in[0];
  const float* xs = (const float*)d_in[1];
  const float* ef = (const float*)d_in[2];
  const int*   ei = (const int*)d_in[3];

  const int N = in_sizes[0] / HDIM;
  const int E = in_sizes[3] / 2;

  float* out = (float*)d_out;          // output buffer is float32

  const bool sizes_ok =
      n_in == 24 &&
      in_sizes[0] == N * HDIM && in_sizes[1] == N * SDIM &&
      in_sizes[2] == E * FDIM && in_sizes[3] == 2 * E &&
      in_sizes[4] == WATT * KA && in_sizes[5] == WATT &&
      in_sizes[6] == WATT && in_sizes[7] == 1 &&
      in_sizes[12] == KG * KG && in_sizes[13] == KG &&
      in_sizes[14] == HDIM * KG && in_sizes[15] == HDIM &&
      out_size == 3 * N * HDIM + 2 * E;
  if (!sizes_ok) {
    sentinel_kernel<<<(out_size + 255) / 256, 256, 0, stream>>>(out, out_size, 777.0f);
    return;
  }

  // ws: pe[E] | denom[N] | fwdm[N*96] | revm[N*96] | Bfrag[NFRAG*4 u32]
  const size_t bfrag_u32 = (size_t)NFRAG * 4;
  const size_t needed =
      ((size_t)E + N + 2 * (size_t)N * HDIM + bfrag_u32) * sizeof(float);
  if (ws_size < needed) {
    sentinel_kernel<<<(out_size + 255) / 256, 256, 0, stream>>>(out, out_size, 12345.0f);
    return;
  }
  float* pe    = (float*)d_ws;
  float* denom = pe + E;
  float* fwdm  = denom + N;
  float* revm  = fwdm + (size_t)N * HDIM;
  u32*   Bfrag = (u32*)(revm + (size_t)N * HDIM);

  float* out_update = out;                         // [N,96]
  float* out_fwdw   = out + (size_t)N * HDIM;      // [E]
  float* out_revw   = out_fwdw + E;                // [E]
  float* out_z      = out_revw + E;                // [N,96]
  float* out_r      = out_z + (size_t)N * HDIM;    // [N,96]

  // zero denom + fwdm + revm (contiguous)
  (void)hipMemsetAsync(denom, 0,
      ((size_t)N + 2 * (size_t)N * HDIM) * sizeof(float), stream);

  // weight prep: fp32 W1 -> bf16 MFMA fragments (rev permutation folded in)
  w_prep<<<(NFRAG + 255) / 256, 256, 0, stream>>>(
      (const float*)d_in[4], (const float*)d_in[8], Bfrag);

  edge_kernel<<<(E + 63) / 64, 256, 0, stream>>>(
      x, xs, ef, ei, (const u16*)Bfrag,
      (const float*)d_in[5], (const float*)d_in[6], (const float*)d_in[7],
      (const float*)d_in[9], (const float*)d_in[10], (const float*)d_in[11],
      pe, denom, out_revw, N, E);

  const long long agg_threads = (long long)E * 48;
  t_agg<<<(int)((agg_threads + 255) / 256), 256, 0, stream>>>(
      x, ei, pe, out_revw, denom, fwdm, revm, out_fwdw, N, E);

  const int nblk = (N + 31) / 32;
  node_kernel<0><<<nblk, 256, 0, stream>>>(
      x, fwdm, revm,
      (const float*)d_in[12], (const float*)d_in[13],
      (const float*)d_in[14], (const float*)d_in[15],
      nullptr, nullptr, out_r, N);
  node_kernel<1><<<nblk, 256, 0, stream>>>(
      x, fwdm, revm,
      (const float*)d_in[16], (const float*)d_in[17],
      (const float*)d_in[18], (const float*)d_in[19],
      nullptr, nullptr, out_z, N);
  node_kernel<2><<<nblk, 256, 0, stream>>>(
      x, fwdm, revm,
      (const float*)d_in[20], (const float*)d_in[21],
      (const float*)d_in[22], (const float*)d_in[23],
      out_r, out_z, out_update, N);
}

// Round 2
// 1947.656 us; speedup vs baseline: 2.1706x; 1.3554x over previous
//
#include <hip/hip_runtime.h>
#include <math.h>

typedef unsigned short u16;
typedef unsigned int   u32;

#define HDIM 96
#define SDIM 48
#define FDIM 24
#define KA   312      // 2H + 2S + F
#define WATT 192
#define KG   288      // 3H

// edge MFMA tiling
#define AS_E  328     // edge A LDS row stride in u16 (656 B, 16B-aligned)
#define KT_A  10      // K-steps of 32 (K padded 312 -> 320)
#define KT_G  9       // node K-steps (288)

#define NFRAG (2 * KT_A * 12 * 64)   // #16B fragments in prepped W1 (both mlps)

typedef __attribute__((ext_vector_type(8))) __bf16 bf16x8;
typedef __attribute__((ext_vector_type(4))) float  f32x4;

__device__ __forceinline__ u16 f2bf(float f) {
  u32 u = __float_as_uint(f);
  u = (u + 0x7FFFu + ((u >> 16) & 1u)) >> 16;   // RNE
  return (u16)u;
}
__device__ __forceinline__ u32 pack2(float a, float b) {
  return (u32)f2bf(a) | ((u32)f2bf(b) << 16);
}
__device__ __forceinline__ f32x4 mfma_bf16(bf16x8 a, bf16x8 b, f32x4 c) {
  return __builtin_amdgcn_mfma_f32_16x16x32_bf16(a, b, c, 0, 0, 0);
}

// ===========================================================================
// Weight prep: convert fwd/rev W1 (fp32, [192 x 312]) to bf16 MFMA fragments
// in workspace, once per launch. Fragment (mlp, kt, nt, lane(q,c)) holds
// W1bf[n = nt*16+c][k = kt*32 + q*8 .. +8] (16 B). rev input-permutation
// (fp32-pair sigma: [0,48)<->[48,96), [96,120)<->[120,144)) folded in here.
// ===========================================================================
__global__ __launch_bounds__(256) void w_prep(
    const float* __restrict__ fW1, const float* __restrict__ rW1,
    u32* __restrict__ Bfrag)
{
  const int idx = blockIdx.x * 256 + threadIdx.x;
  if (idx >= NFRAG) return;
  const int lane = idx & 63;
  const int frag = idx >> 6;
  const int nt   = frag % 12;
  const int rest = frag / 12;
  const int kt   = rest % KT_A;
  const int mlp  = rest / KT_A;
  const int q = lane >> 4, c = lane & 15;
  const int n  = nt * 16 + c;
  const int p0 = kt * 16 + q * 4;            // first fp32-pair index
  const float* W = mlp ? rW1 : fW1;
  u32 v[4];
#pragma unroll
  for (int w = 0; w < 4; ++w) {
    const int p = p0 + w;
    u32 val = 0u;
    if (p < 156) {
      int src = p;
      if (mlp) {                             // sigma (pair units)
        if (src < 48)       src += 48;
        else if (src < 96)  src -= 48;
        else if (src < 120) src += 24;
        else if (src < 144) src -= 24;
      }
      const float2 wv = *(const float2*)(W + (size_t)n * KA + 2 * src);
      val = pack2(wv.x, wv.y);
    }
    v[w] = val;
  }
  ((uint4*)Bfrag)[idx] = make_uint4(v[0], v[1], v[2], v[3]);
}

// ===========================================================================
// Edge kernel (MFMA): 64 edges/block, 256 threads (4 waves). Barrier-free
// K-loop with register-resident W1 fragments (see R0). Epilogue writes
// pe[e] (softmax numerator, un-normalized) and out_revw[e] (sigmoid).
// NO atomics here any more: denominators are computed in the CSR gather.
// ===========================================================================
__global__ __launch_bounds__(256, 2) void edge_kernel(
    const float* __restrict__ x, const float* __restrict__ xs,
    const float* __restrict__ ef, const int* __restrict__ ei,
    const u16* __restrict__ Bfrag,
    const float* __restrict__ fb1, const float* __restrict__ fW2,
    const float* __restrict__ fb2,
    const float* __restrict__ rb1, const float* __restrict__ rW2,
    const float* __restrict__ rb2,
    float* __restrict__ pe, float* __restrict__ out_revw, int N, int E)
{
  __shared__ __align__(16) u16 Alds[64 * AS_E];   // 41,984 B
  __shared__ float red[4][64];                    //  1,024 B

  const int tid  = threadIdx.x;
  const int wave = tid >> 6, lane = tid & 63;
  const int q = lane >> 4, c = lane & 15;
  const int e0 = blockIdx.x * 64;

  // ---- gather A as bf16 pairs (pair index p in [0,160), pad >=156 zero) ---
  {
    u32* Aw = (u32*)Alds;
    const int el = tid >> 2, sub = tid & 3;
    const int e = min(e0 + el, E - 1);
    int s = ei[e], d = ei[(size_t)E + e];
    s = min(max(s, 0), N - 1); d = min(max(d, 0), N - 1);
    for (int p = sub; p < 160; p += 4) {
      const int j = 2 * p;                        // fp32 element index
      float2 v = make_float2(0.f, 0.f);
      if (j < 96)       v = *(const float2*)(x  + (size_t)s * 96 + j);
      else if (j < 192) v = *(const float2*)(x  + (size_t)d * 96 + (j - 96));
      else if (j < 240) v = *(const float2*)(xs + (size_t)s * 48 + (j - 192));
      else if (j < 288) v = *(const float2*)(xs + (size_t)d * 48 + (j - 240));
      else if (j < 312) v = *(const float2*)(ef + (size_t)e * 24 + (j - 288));
      Aw[el * (AS_E / 2) + p] = pack2(v.x, v.y);
    }
  }
  __syncthreads();                                // A ready (read-only after)

  const bf16x8* __restrict__ Bf = (const bf16x8*)Bfrag;

  for (int mlp = 0; mlp < 2; ++mlp) {
    f32x4 acc[4][3];
#pragma unroll
    for (int m = 0; m < 4; ++m)
      for (int t = 0; t < 3; ++t)
        acc[m][t] = (f32x4){0.f, 0.f, 0.f, 0.f};

#pragma unroll
    for (int kt = 0; kt < KT_A; ++kt) {
      bf16x8 a[4];
#pragma unroll
      for (int m = 0; m < 4; ++m)
        a[m] = *(const bf16x8*)&Alds[(m * 16 + c) * AS_E + kt * 32 + q * 8];
#pragma unroll
      for (int t = 0; t < 3; ++t) {
        const bf16x8 b =
            Bf[(((mlp * KT_A + kt) * 12) + wave * 3 + t) * 64 + lane];
#pragma unroll
        for (int m = 0; m < 4; ++m)
          acc[m][t] = mfma_bf16(a[m], b, acc[m][t]);
      }
    }

    // ---- epilogue: bias + relu + dot(W2), reduce across 16 col-lanes ----
    const float* b1p = mlp ? rb1 : fb1;
    const float* W2p = mlp ? rW2 : fW2;
    float p[4][4];
#pragma unroll
    for (int m = 0; m < 4; ++m)
      for (int r = 0; r < 4; ++r) p[m][r] = 0.f;
#pragma unroll
    for (int t = 0; t < 3; ++t) {
      const int n = (wave * 3 + t) * 16 + c;
      const float b1f = b1p[n];
      const float w2f = W2p[n];
#pragma unroll
      for (int m = 0; m < 4; ++m)
        for (int r = 0; r < 4; ++r) {
          float h = acc[m][t][r] + b1f;
          h = h > 0.f ? h : 0.f;
          p[m][r] += h * w2f;
        }
    }
    for (int off = 1; off <= 8; off <<= 1)
#pragma unroll
      for (int m = 0; m < 4; ++m)
        for (int r = 0; r < 4; ++r)
          p[m][r] += __shfl_xor(p[m][r], off, 64);

    __syncthreads();                    // red safe to overwrite
    if (c == 0) {
#pragma unroll
      for (int m = 0; m < 4; ++m)
        for (int r = 0; r < 4; ++r)
          red[wave][m * 16 + q * 4 + r] = p[m][r];
    }
    __syncthreads();

    if (tid < 64 && e0 + tid < E) {
      float raw = red[0][tid] + red[1][tid] + red[2][tid] + red[3][tid];
      const int e = e0 + tid;
      if (mlp == 0) {
        raw += fb2[0];
        const float lr = raw > 0.f ? raw : 0.01f * raw;      // leaky_relu
        pe[e] = __expf(lr * 0.10206207261596575f);           // /sqrt(96)
      } else {
        raw += rb2[0];
        out_revw[e] = 1.f / (1.f + __expf(-raw));
      }
    }
  }
}

// ===========================================================================
// CSR build: counting sort of edges by dest (fwd) and by src (rev).
// hist -> block scan -> block-offset scan -> add offsets -> fill.
// ===========================================================================
__global__ __launch_bounds__(256) void k_hist(
    const int* __restrict__ ei, int* __restrict__ deg_d,
    int* __restrict__ deg_s, int N, int E)
{
  const int e = blockIdx.x * 256 + threadIdx.x;
  if (e >= E) return;
  const int s = min(max(ei[e], 0), N - 1);
  const int d = min(max(ei[(size_t)E + e], 0), N - 1);
  atomicAdd(&deg_d[d], 1);
  atomicAdd(&deg_s[s], 1);
}

__global__ __launch_bounds__(256) void k_scan1(
    const int* __restrict__ deg_d, const int* __restrict__ deg_s,
    int* __restrict__ start_d, int* __restrict__ start_s,
    int* __restrict__ bsum_d, int* __restrict__ bsum_s, int N)
{
  __shared__ int sh[256];
  const int t = threadIdx.x, i = blockIdx.x * 256 + t;
  {
    const int v = (i < N) ? deg_d[i] : 0;
    sh[t] = v; __syncthreads();
    for (int off = 1; off < 256; off <<= 1) {
      const int u = (t >= off) ? sh[t - off] : 0;
      __syncthreads();
      sh[t] += u;
      __syncthreads();
    }
    if (i < N) start_d[i] = sh[t] - v;          // exclusive within block
    if (t == 255) bsum_d[blockIdx.x] = sh[255];
    __syncthreads();
  }
  {
    const int v = (i < N) ? deg_s[i] : 0;
    sh[t] = v; __syncthreads();
    for (int off = 1; off < 256; off <<= 1) {
      const int u = (t >= off) ? sh[t - off] : 0;
      __syncthreads();
      sh[t] += u;
      __syncthreads();
    }
    if (i < N) start_s[i] = sh[t] - v;
    if (t == 255) bsum_s[blockIdx.x] = sh[255];
  }
}

__global__ void k_scan2(int* bsum_d, int* bsum_s, int nb) {
  if (threadIdx.x == 0) {
    int r = 0;
    for (int b = 0; b < nb; ++b) { const int t = bsum_d[b]; bsum_d[b] = r; r += t; }
  } else if (threadIdx.x == 1) {
    int r = 0;
    for (int b = 0; b < nb; ++b) { const int t = bsum_s[b]; bsum_s[b] = r; r += t; }
  }
}

__global__ __launch_bounds__(256) void k_scan3(
    int* __restrict__ start_d, int* __restrict__ start_s,
    const int* __restrict__ bsum_d, const int* __restrict__ bsum_s,
    int* __restrict__ pos_d, int* __restrict__ pos_s, int N)
{
  const int i = blockIdx.x * 256 + threadIdx.x;
  if (i >= N) return;
  const int b = i >> 8;
  const int vd = start_d[i] + bsum_d[b]; start_d[i] = vd; pos_d[i] = vd;
  const int vs = start_s[i] + bsum_s[b]; start_s[i] = vs; pos_s[i] = vs;
}

__global__ __launch_bounds__(256) void k_fill(
    const int* __restrict__ ei, int* __restrict__ pos_d,
    int* __restrict__ pos_s, int* __restrict__ eidx_d,
    int* __restrict__ eidx_s, int N, int E)
{
  const int e = blockIdx.x * 256 + threadIdx.x;
  if (e >= E) return;
  const int s = min(max(ei[e], 0), N - 1);
  const int d = min(max(ei[(size_t)E + e], 0), N - 1);
  eidx_d[atomicAdd(&pos_d[d], 1)] = e;
  eidx_s[atomicAdd(&pos_s[s], 1)] = e;
}

// ===========================================================================
// Gather-aggregate. 32-lane group per node (8 nodes / 256-thread block).
// DIR 0 (fwd, segmented by dest): pass 1 computes softmax denom over the
// segment + writes out_fwdw; pass 2 accumulates w * x[src] into registers,
// one plain coalesced row write. DIR 1 (rev, by src): w = sigmoid (revw),
// accumulates w * x[dest] into revm. After fill, pos[n] = segment end.
// ===========================================================================
template <int DIR>
__global__ __launch_bounds__(256) void k_agg(
    const float* __restrict__ x, const int* __restrict__ ei,
    const float* __restrict__ pe, const float* __restrict__ revw,
    const int* __restrict__ start, const int* __restrict__ endp,
    const int* __restrict__ eidx,
    float* __restrict__ outm, float* __restrict__ out_fwdw, int N, int E)
{
  const int g = threadIdx.x >> 5;        // group 0..7
  const int l = threadIdx.x & 31;
  const int n = blockIdx.x * 8 + g;
  if (n >= N) return;
  const int beg = start[n], end = endp[n];

  float inv = 1.f;
  if (DIR == 0) {
    float sum = 0.f;
    for (int i = beg + l; i < end; i += 32) sum += pe[eidx[i]];
    for (int off = 16; off; off >>= 1) sum += __shfl_xor(sum, off, 32);
    inv = 1.f / (sum + 1e-9f);
    for (int i = beg + l; i < end; i += 32) {
      const int e = eidx[i];
      out_fwdw[e] = pe[e] * inv;
    }
  }

  float a0 = 0.f, a1 = 0.f, a2 = 0.f;
  for (int i = beg; i < end; ++i) {
    const int e = eidx[i];                                   // broadcast
    const float w = (DIR == 0) ? pe[e] * inv : revw[e];      // broadcast
    const int o = (DIR == 0) ? min(max(ei[e], 0), N - 1)
                             : min(max(ei[(size_t)E + e], 0), N - 1);
    const float* xr = x + (size_t)o * 96;
    a0 += w * xr[l];
    a1 += w * xr[l + 32];
    a2 += w * xr[l + 64];
  }
  float* orow = outm + (size_t)n * 96;
  orow[l] = a0; orow[l + 32] = a1; orow[l + 64] = a2;
}

// ===========================================================================
// Node MLP (MFMA): unchanged from R1 (32 nodes/block, 256 threads).
// ===========================================================================
template <int MODE>
__global__ __launch_bounds__(256) void node_kernel(
    const float* __restrict__ x,
    const float* __restrict__ fwdm, const float* __restrict__ revm,
    const float* __restrict__ W1, const float* __restrict__ b1,
    const float* __restrict__ W2, const float* __restrict__ b2,
    const float* __restrict__ rin, const float* __restrict__ zin,
    float* __restrict__ fout, int N)
{
  __shared__ __align__(16) u16 Alds[32 * KG];   // 18,432 B
  __shared__ __align__(16) u16 Hlds[32 * KG];   // 18,432 B
  __shared__ __align__(16) u16 Blds[KG * 32];   // 18,432 B (reused for W2)

  const int tid = threadIdx.x;
  const int wave = tid >> 6, lane = tid & 63;
  const int q = lane >> 4, c = lane & 15;
  const int n0 = blockIdx.x * 32;

  // ---- gather A (144 fp32-pairs per node row) ----
  {
    u32* Aw = (u32*)Alds;
    const int nl = tid >> 3, sub = tid & 7;
    const int node = min(n0 + nl, N - 1);
    for (int p = sub; p < 144; p += 8) {
      const int j = 2 * p;
      float2 v;
      if (j < 96) {
        v = *(const float2*)(x + (size_t)node * 96 + j);
        if (MODE == 2) {
          const float2 r2 = *(const float2*)(rin + (size_t)node * 96 + j);
          v.x *= r2.x; v.y *= r2.y;
        }
      } else if (j < 192) {
        v = *(const float2*)(fwdm + (size_t)node * 96 + (j - 96));
      } else {
        v = *(const float2*)(revm + (size_t)node * 96 + (j - 192));
      }
      Aw[nl * (KG / 2) + p] = pack2(v.x, v.y);
    }
  }

  // ---- layer 1: 288 -> 288 ----
  const int ntc = (wave < 2) ? 5 : 4;           // 18 N-tiles over 4 waves
  f32x4 acc[2][5];
  for (int m = 0; m < 2; ++m)
    for (int t = 0; t < 5; ++t) acc[m][t] = (f32x4){0.f, 0.f, 0.f, 0.f};
  for (int kt = 0; kt < KT_G; ++kt) {
    __syncthreads();
    u32* Bw = (u32*)Blds;
    for (int j = tid; j < KG * 16; j += 256) {
      const int n = j >> 4, kk = j & 15;
      const float2 w = *(const float2*)(W1 + (size_t)n * KG + kt * 32 + kk * 2);
      Bw[j] = pack2(w.x, w.y);
    }
    __syncthreads();
    const bf16x8 a0 = *(const bf16x8*)&Alds[c * KG + kt * 32 + q * 8];
    const bf16x8 a1 = *(const bf16x8*)&Alds[(16 + c) * KG + kt * 32 + q * 8];
    for (int t = 0; t < ntc; ++t) {
      const int nt = wave + 4 * t;
      const bf16x8 b = *(const bf16x8*)&Blds[(nt * 16 + c) * 32 + q * 8];
      acc[0][t] = mfma_bf16(a0, b, acc[0][t]);
      acc[1][t] = mfma_bf16(a1, b, acc[1][t]);
    }
  }
  // bias + relu -> Hlds (bf16)
  for (int t = 0; t < ntc; ++t) {
    const int n = (wave + 4 * t) * 16 + c;
    const float b1f = b1[n];
    for (int m = 0; m < 2; ++m)
      for (int r = 0; r < 4; ++r) {
        float h = acc[m][t][r] + b1f;
        h = h > 0.f ? h : 0.f;
        Hlds[(m * 16 + q * 4 + r) * KG + n] = f2bf(h);
      }
  }

  // ---- layer 2: 288 -> 96 ----
  const int ntc2 = (wave < 2) ? 2 : 1;          // 6 N-tiles over 4 waves
  f32x4 acc2[2][2];
  for (int m = 0; m < 2; ++m)
    for (int t = 0; t < 2; ++t) acc2[m][t] = (f32x4){0.f, 0.f, 0.f, 0.f};
  for (int kt = 0; kt < KT_G; ++kt) {
    __syncthreads();                            // guards Hlds completion (kt==0)
    u32* Bw = (u32*)Blds;
    for (int j = tid; j < HDIM * 16; j += 256) {
      const int n = j >> 4, kk = j & 15;
      const float2 w = *(const float2*)(W2 + (size_t)n * KG + kt * 32 + kk * 2);
      Bw[j] = pack2(w.x, w.y);
    }
    __syncthreads();
    const bf16x8 a0 = *(const bf16x8*)&Hlds[c * KG + kt * 32 + q * 8];
    const bf16x8 a1 = *(const bf16x8*)&Hlds[(16 + c) * KG + kt * 32 + q * 8];
    for (int t = 0; t < ntc2; ++t) {
      const int nt = wave + 4 * t;
      const bf16x8 b = *(const bf16x8*)&Blds[(nt * 16 + c) * 32 + q * 8];
      acc2[0][t] = mfma_bf16(a0, b, acc2[0][t]);
      acc2[1][t] = mfma_bf16(a1, b, acc2[1][t]);
    }
  }

  // ---- epilogue ----
  for (int t = 0; t < ntc2; ++t) {
    const int n2 = (wave + 4 * t) * 16 + c;
    const float b2f = b2[n2];
    for (int m = 0; m < 2; ++m)
      for (int r = 0; r < 4; ++r) {
        const int row = m * 16 + q * 4 + r;
        const int node = n0 + row;
        if (node < N) {
          const float v = acc2[m][t][r] + b2f;
          if (MODE < 2) {
            fout[(size_t)node * HDIM + n2] = 1.f / (1.f + __expf(-v));
          } else {
            const float ct = tanhf(v);
            const float z = zin[(size_t)node * HDIM + n2];
            const float xv = x[(size_t)node * HDIM + n2];
            fout[(size_t)node * HDIM + n2] = (1.f - z) * xv + z * ct;
          }
        }
      }
  }
}

__global__ void sentinel_kernel(float* out, int n, float val) {
  const int i = blockIdx.x * 256 + threadIdx.x;
  if (i < n) out[i] = val;
}

// ---------------------------------------------------------------------------
extern "C" void kernel_launch(void* const* d_in, const int* in_sizes, int n_in,
                              void* d_out, int out_size, void* d_ws, size_t ws_size,
                              hipStream_t stream) {
  const float* x  = (const float*)d_in[0];
  const float* xs = (const float*)d_in[1];
  const float* ef = (const float*)d_in[2];
  const int*   ei = (const int*)d_in[3];

  const int N = in_sizes[0] / HDIM;
  const int E = in_sizes[3] / 2;

  float* out = (float*)d_out;          // output buffer is float32

  const int NB = (N + 255) / 256;      // scan blocks (<=1024 supported)

  const bool sizes_ok =
      n_in == 24 && NB <= 1024 &&
      in_sizes[0] == N * HDIM && in_sizes[1] == N * SDIM &&
      in_sizes[2] == E * FDIM && in_sizes[3] == 2 * E &&
      in_sizes[4] == WATT * KA && in_sizes[5] == WATT &&
      in_sizes[6] == WATT && in_sizes[7] == 1 &&
      in_sizes[12] == KG * KG && in_sizes[13] == KG &&
      in_sizes[14] == HDIM * KG && in_sizes[15] == HDIM &&
      out_size == 3 * N * HDIM + 2 * E;
  if (!sizes_ok) {
    sentinel_kernel<<<(out_size + 255) / 256, 256, 0, stream>>>(out, out_size, 777.0f);
    return;
  }

  // ws layout (4-byte units):
  // pe[E] | fwdm[N*96] | revm[N*96] | Bfrag[NFRAG*4] |
  // deg_d[N] deg_s[N] | start_d[N] start_s[N] | pos_d[N] pos_s[N] |
  // bsum_d[1024] bsum_s[1024] | eidx_d[E] eidx_s[E]
  const size_t needed =
      ((size_t)E + 2 * (size_t)N * HDIM + (size_t)NFRAG * 4 +
       6 * (size_t)N + 2048 + 2 * (size_t)E) * 4;
  if (ws_size < needed) {
    sentinel_kernel<<<(out_size + 255) / 256, 256, 0, stream>>>(out, out_size, 12345.0f);
    return;
  }
  float* pe    = (float*)d_ws;
  float* fwdm  = pe + E;
  float* revm  = fwdm + (size_t)N * HDIM;
  u32*   Bfrag = (u32*)(revm + (size_t)N * HDIM);
  int* deg_d   = (int*)(Bfrag + (size_t)NFRAG * 4);
  int* deg_s   = deg_d + N;
  int* start_d = deg_s + N;
  int* start_s = start_d + N;
  int* pos_d   = start_s + N;
  int* pos_s   = pos_d + N;
  int* bsum_d  = pos_s + N;
  int* bsum_s  = bsum_d + 1024;
  int* eidx_d  = bsum_s + 1024;
  int* eidx_s  = eidx_d + E;

  float* out_update = out;                         // [N,96]
  float* out_fwdw   = out + (size_t)N * HDIM;      // [E]
  float* out_revw   = out_fwdw + E;                // [E]
  float* out_z      = out_revw + E;                // [N,96]
  float* out_r      = out_z + (size_t)N * HDIM;    // [N,96]

  // zero degree histograms only (fwdm/revm are fully overwritten by k_agg)
  (void)hipMemsetAsync(deg_d, 0, 2 * (size_t)N * sizeof(int), stream);

  // weight prep: fp32 W1 -> bf16 MFMA fragments (rev permutation folded in)
  w_prep<<<(NFRAG + 255) / 256, 256, 0, stream>>>(
      (const float*)d_in[4], (const float*)d_in[8], Bfrag);

  // CSR build (independent of edge MLP outputs)
  const int eblk = (E + 255) / 256;
  k_hist<<<eblk, 256, 0, stream>>>(ei, deg_d, deg_s, N, E);
  k_scan1<<<NB, 256, 0, stream>>>(deg_d, deg_s, start_d, start_s,
                                  bsum_d, bsum_s, N);
  k_scan2<<<1, 64, 0, stream>>>(bsum_d, bsum_s, NB);
  k_scan3<<<NB, 256, 0, stream>>>(start_d, start_s, bsum_d, bsum_s,
                                  pos_d, pos_s, N);
  k_fill<<<eblk, 256, 0, stream>>>(ei, pos_d, pos_s, eidx_d, eidx_s, N, E);

  // edge MLPs
  edge_kernel<<<(E + 63) / 64, 256, 0, stream>>>(
      x, xs, ef, ei, (const u16*)Bfrag,
      (const float*)d_in[5], (const float*)d_in[6], (const float*)d_in[7],
      (const float*)d_in[9], (const float*)d_in[10], (const float*)d_in[11],
      pe, out_revw, N, E);

  // gather-aggregate (replaces atomic t_agg); pos_* hold segment ends
  const int ablk = (N + 7) / 8;
  k_agg<0><<<ablk, 256, 0, stream>>>(x, ei, pe, out_revw, start_d, pos_d,
                                     eidx_d, fwdm, out_fwdw, N, E);
  k_agg<1><<<ablk, 256, 0, stream>>>(x, ei, pe, out_revw, start_s, pos_s,
                                     eidx_s, revm, out_fwdw, N, E);

  // node MLPs
  const int nblk = (N + 31) / 32;
  node_kernel<0><<<nblk, 256, 0, stream>>>(
      x, fwdm, revm,
      (const float*)d_in[12], (const float*)d_in[13],
      (const float*)d_in[14], (const float*)d_in[15],
      nullptr, nullptr, out_r, N);
  node_kernel<1><<<nblk, 256, 0, stream>>>(
      x, fwdm, revm,
      (const float*)d_in[16], (const float*)d_in[17],
      (const float*)d_in[18], (const float*)d_in[19],
      nullptr, nullptr, out_z, N);
  node_kernel<2><<<nblk, 256, 0, stream>>>(
      x, fwdm, revm,
      (const float*)d_in[20], (const float*)d_in[21],
      (const float*)d_in[22], (const float*)d_in[23],
      out_r, out_z, out_update, N);
}

// Round 3
// 1164.172 us; speedup vs baseline: 3.6315x; 1.6730x over previous
//
#include <hip/hip_runtime.h>
#include <math.h>

typedef unsigned short u16;
typedef unsigned int   u32;

#define HDIM 96
#define SDIM 48
#define FDIM 24
#define KA   312      // 2H + 2S + F
#define WATT 192
#define KG   288      // 3H

// edge MFMA tiling
#define AS_E  328     // edge A LDS row stride in u16 (656 B; 164 dw = 4 mod 32 -> 2-way)
#define KT_A  10      // K-steps of 32 (K padded 312 -> 320)
#define KT_G  9       // node K-steps (288)
#define NS    296     // node LDS row stride in u16 (148 dw = 20 mod 32 -> 2-way)

#define NFRAG (2 * KT_A * 12 * 64)   // edge W1 fragments (uint4 count)
#define W1F_Q (KT_G * 18 * 64)       // 10368 uint4 per node W1
#define W2F_Q (KT_G * 6 * 64)        //  3456 uint4 per node W2
#define NODEF_Q (3 * (W1F_Q + W2F_Q))

typedef __attribute__((ext_vector_type(8))) __bf16 bf16x8;
typedef __attribute__((ext_vector_type(4))) float  f32x4;

__device__ __forceinline__ u16 f2bf(float f) {
  u32 u = __float_as_uint(f);
  u = (u + 0x7FFFu + ((u >> 16) & 1u)) >> 16;   // RNE
  return (u16)u;
}
__device__ __forceinline__ float bf2f(u16 v) {
  return __uint_as_float((u32)v << 16);
}
__device__ __forceinline__ u32 pack2(float a, float b) {
  return (u32)f2bf(a) | ((u32)f2bf(b) << 16);
}
__device__ __forceinline__ f32x4 mfma_bf16(bf16x8 a, bf16x8 b, f32x4 c) {
  return __builtin_amdgcn_mfma_f32_16x16x32_bf16(a, b, c, 0, 0, 0);
}

// ===========================================================================
// Edge W1 prep (unchanged from R1): fp32 [192x312] -> bf16 fragments,
// rev input-permutation folded in, K padded 312->320.
// ===========================================================================
__global__ __launch_bounds__(256) void w_prep(
    const float* __restrict__ fW1, const float* __restrict__ rW1,
    uint4* __restrict__ Bfrag)
{
  const int idx = blockIdx.x * 256 + threadIdx.x;
  if (idx >= NFRAG) return;
  const int lane = idx & 63;
  const int frag = idx >> 6;
  const int nt   = frag % 12;
  const int rest = frag / 12;
  const int kt   = rest % KT_A;
  const int mlp  = rest / KT_A;
  const int q = lane >> 4, c = lane & 15;
  const int n  = nt * 16 + c;
  const int p0 = kt * 16 + q * 4;
  const float* W = mlp ? rW1 : fW1;
  u32 v[4];
#pragma unroll
  for (int w = 0; w < 4; ++w) {
    const int p = p0 + w;
    u32 val = 0u;
    if (p < 156) {
      int src = p;
      if (mlp) {
        if (src < 48)       src += 48;
        else if (src < 96)  src -= 48;
        else if (src < 120) src += 24;
        else if (src < 144) src -= 24;
      }
      const float2 wv = *(const float2*)(W + (size_t)n * KA + 2 * src);
      val = pack2(wv.x, wv.y);
    }
    v[w] = val;
  }
  Bfrag[idx] = make_uint4(v[0], v[1], v[2], v[3]);
}

// ===========================================================================
// Node weight prep: W [NT*16 x 288] fp32 -> bf16 fragments [kt][nt][lane].
// ===========================================================================
__global__ __launch_bounds__(256) void w_prep_node(
    const float* __restrict__ W, uint4* __restrict__ outf, int NT)
{
  const int nfrag = KT_G * NT * 64;
  const int idx = blockIdx.x * 256 + threadIdx.x;
  if (idx >= nfrag) return;
  const int lane = idx & 63;
  const int frag = idx >> 6;
  const int nt = frag % NT, kt = frag / NT;
  const int q = lane >> 4, c = lane & 15;
  const int n = nt * 16 + c;
  const int k0 = kt * 32 + q * 8;
  u32 v[4];
#pragma unroll
  for (int w = 0; w < 4; ++w) {
    const float2 wv = *(const float2*)(W + (size_t)n * KG + k0 + 2 * w);
    v[w] = pack2(wv.x, wv.y);
  }
  outf[idx] = make_uint4(v[0], v[1], v[2], v[3]);
}

// ===========================================================================
// Activation prep: x [N x 96] and xs [N x 48] fp32 -> bf16 (packed u32 pairs).
// ===========================================================================
__global__ __launch_bounds__(256) void x_prep(
    const float* __restrict__ x, const float* __restrict__ xs,
    u32* __restrict__ xb, u32* __restrict__ xsb, int N)
{
  const int i = blockIdx.x * 256 + threadIdx.x;
  const int nx = N * 48;
  if (i < nx) {
    const float2 v = ((const float2*)x)[i];
    xb[i] = pack2(v.x, v.y);
  } else if (i < nx + N * 24) {
    const float2 v = ((const float2*)xs)[i - nx];
    xsb[i - nx] = pack2(v.x, v.y);
  }
}

// ===========================================================================
// Edge kernel: 64 edges/block, 4 waves. A gathered as u32 copies from
// pre-converted bf16 x/xs (only ef needs fp32->bf16 pack). W1 fragments in
// registers from L2 (barrier-free K-loop). Epilogue -> pe / out_revw.
// ===========================================================================
__global__ __launch_bounds__(256, 2) void edge_kernel(
    const u32* __restrict__ xb, const u32* __restrict__ xsb,
    const float* __restrict__ ef, const int* __restrict__ ei,
    const u16* __restrict__ Bfrag,
    const float* __restrict__ fb1, const float* __restrict__ fW2,
    const float* __restrict__ fb2,
    const float* __restrict__ rb1, const float* __restrict__ rW2,
    const float* __restrict__ rb2,
    float* __restrict__ pe, float* __restrict__ out_revw, int N, int E)
{
  __shared__ __align__(16) u16 Alds[64 * AS_E];   // 41,984 B
  __shared__ float red[4][64];

  const int tid  = threadIdx.x;
  const int wave = tid >> 6, lane = tid & 63;
  const int q = lane >> 4, c = lane & 15;
  const int e0 = blockIdx.x * 64;

  // ---- gather A (u32 copies; pair index p in [0,160), pad >=156 zero) ----
  {
    u32* Aw = (u32*)Alds;
    const int el = tid >> 2, sub = tid & 3;
    const int e = min(e0 + el, E - 1);
    int s = ei[e], d = ei[(size_t)E + e];
    s = min(max(s, 0), N - 1); d = min(max(d, 0), N - 1);
    const u32* xs_ = xb  + (size_t)s * 48;
    const u32* xd_ = xb  + (size_t)d * 48;
    const u32* ss_ = xsb + (size_t)s * 24;
    const u32* sd_ = xsb + (size_t)d * 24;
    for (int p = sub; p < 160; p += 4) {
      u32 v = 0u;
      if (p < 48)       v = xs_[p];
      else if (p < 96)  v = xd_[p - 48];
      else if (p < 120) v = ss_[p - 96];
      else if (p < 144) v = sd_[p - 120];
      else if (p < 156) {
        const float2 w = *(const float2*)(ef + (size_t)e * 24 + 2 * (p - 144));
        v = pack2(w.x, w.y);
      }
      Aw[el * (AS_E / 2) + p] = v;
    }
  }
  __syncthreads();                                // A ready (read-only after)

  const bf16x8* __restrict__ Bf = (const bf16x8*)Bfrag;

  for (int mlp = 0; mlp < 2; ++mlp) {
    f32x4 acc[4][3];
#pragma unroll
    for (int m = 0; m < 4; ++m)
      for (int t = 0; t < 3; ++t)
        acc[m][t] = (f32x4){0.f, 0.f, 0.f, 0.f};

#pragma unroll
    for (int kt = 0; kt < KT_A; ++kt) {
      bf16x8 a[4];
#pragma unroll
      for (int m = 0; m < 4; ++m)
        a[m] = *(const bf16x8*)&Alds[(m * 16 + c) * AS_E + kt * 32 + q * 8];
#pragma unroll
      for (int t = 0; t < 3; ++t) {
        const bf16x8 b =
            Bf[(((mlp * KT_A + kt) * 12) + wave * 3 + t) * 64 + lane];
#pragma unroll
        for (int m = 0; m < 4; ++m)
          acc[m][t] = mfma_bf16(a[m], b, acc[m][t]);
      }
    }

    // ---- epilogue: bias + relu + dot(W2), reduce across 16 col-lanes ----
    const float* b1p = mlp ? rb1 : fb1;
    const float* W2p = mlp ? rW2 : fW2;
    float p[4][4];
#pragma unroll
    for (int m = 0; m < 4; ++m)
      for (int r = 0; r < 4; ++r) p[m][r] = 0.f;
#pragma unroll
    for (int t = 0; t < 3; ++t) {
      const int n = (wave * 3 + t) * 16 + c;
      const float b1f = b1p[n];
      const float w2f = W2p[n];
#pragma unroll
      for (int m = 0; m < 4; ++m)
        for (int r = 0; r < 4; ++r) {
          float h = acc[m][t][r] + b1f;
          h = h > 0.f ? h : 0.f;
          p[m][r] += h * w2f;
        }
    }
    for (int off = 1; off <= 8; off <<= 1)
#pragma unroll
      for (int m = 0; m < 4; ++m)
        for (int r = 0; r < 4; ++r)
          p[m][r] += __shfl_xor(p[m][r], off, 64);

    __syncthreads();
    if (c == 0) {
#pragma unroll
      for (int m = 0; m < 4; ++m)
        for (int r = 0; r < 4; ++r)
          red[wave][m * 16 + q * 4 + r] = p[m][r];
    }
    __syncthreads();

    if (tid < 64 && e0 + tid < E) {
      float raw = red[0][tid] + red[1][tid] + red[2][tid] + red[3][tid];
      const int e = e0 + tid;
      if (mlp == 0) {
        raw += fb2[0];
        const float lr = raw > 0.f ? raw : 0.01f * raw;      // leaky_relu
        pe[e] = __expf(lr * 0.10206207261596575f);           // /sqrt(96)
      } else {
        raw += rb2[0];
        out_revw[e] = 1.f / (1.f + __expf(-raw));
      }
    }
  }
}

// ===========================================================================
// CSR build (unchanged from R2).
// ===========================================================================
__global__ __launch_bounds__(256) void k_hist(
    const int* __restrict__ ei, int* __restrict__ deg_d,
    int* __restrict__ deg_s, int N, int E)
{
  const int e = blockIdx.x * 256 + threadIdx.x;
  if (e >= E) return;
  const int s = min(max(ei[e], 0), N - 1);
  const int d = min(max(ei[(size_t)E + e], 0), N - 1);
  atomicAdd(&deg_d[d], 1);
  atomicAdd(&deg_s[s], 1);
}

__global__ __launch_bounds__(256) void k_scan1(
    const int* __restrict__ deg_d, const int* __restrict__ deg_s,
    int* __restrict__ start_d, int* __restrict__ start_s,
    int* __restrict__ bsum_d, int* __restrict__ bsum_s, int N)
{
  __shared__ int sh[256];
  const int t = threadIdx.x, i = blockIdx.x * 256 + t;
  {
    const int v = (i < N) ? deg_d[i] : 0;
    sh[t] = v; __syncthreads();
    for (int off = 1; off < 256; off <<= 1) {
      const int u = (t >= off) ? sh[t - off] : 0;
      __syncthreads();
      sh[t] += u;
      __syncthreads();
    }
    if (i < N) start_d[i] = sh[t] - v;
    if (t == 255) bsum_d[blockIdx.x] = sh[255];
    __syncthreads();
  }
  {
    const int v = (i < N) ? deg_s[i] : 0;
    sh[t] = v; __syncthreads();
    for (int off = 1; off < 256; off <<= 1) {
      const int u = (t >= off) ? sh[t - off] : 0;
      __syncthreads();
      sh[t] += u;
      __syncthreads();
    }
    if (i < N) start_s[i] = sh[t] - v;
    if (t == 255) bsum_s[blockIdx.x] = sh[255];
  }
}

__global__ void k_scan2(int* bsum_d, int* bsum_s, int nb) {
  if (threadIdx.x == 0) {
    int r = 0;
    for (int b = 0; b < nb; ++b) { const int t = bsum_d[b]; bsum_d[b] = r; r += t; }
  } else if (threadIdx.x == 1) {
    int r = 0;
    for (int b = 0; b < nb; ++b) { const int t = bsum_s[b]; bsum_s[b] = r; r += t; }
  }
}

__global__ __launch_bounds__(256) void k_scan3(
    int* __restrict__ start_d, int* __restrict__ start_s,
    const int* __restrict__ bsum_d, const int* __restrict__ bsum_s,
    int* __restrict__ pos_d, int* __restrict__ pos_s, int N)
{
  const int i = blockIdx.x * 256 + threadIdx.x;
  if (i >= N) return;
  const int b = i >> 8;
  const int vd = start_d[i] + bsum_d[b]; start_d[i] = vd; pos_d[i] = vd;
  const int vs = start_s[i] + bsum_s[b]; start_s[i] = vs; pos_s[i] = vs;
}

__global__ __launch_bounds__(256) void k_fill(
    const int* __restrict__ ei, int* __restrict__ pos_d,
    int* __restrict__ pos_s, int* __restrict__ eidx_d,
    int* __restrict__ eidx_s, int N, int E)
{
  const int e = blockIdx.x * 256 + threadIdx.x;
  if (e >= E) return;
  const int s = min(max(ei[e], 0), N - 1);
  const int d = min(max(ei[(size_t)E + e], 0), N - 1);
  eidx_d[atomicAdd(&pos_d[d], 1)] = e;
  eidx_s[atomicAdd(&pos_s[s], 1)] = e;
}

// ===========================================================================
// Gather-aggregate (R2 structure); now writes bf16 message rows directly
// (identical rounding to the old node-gather pack2 of fp32 sums).
// ===========================================================================
template <int DIR>
__global__ __launch_bounds__(256) void k_agg(
    const float* __restrict__ x, const int* __restrict__ ei,
    const float* __restrict__ pe, const float* __restrict__ revw,
    const int* __restrict__ start, const int* __restrict__ endp,
    const int* __restrict__ eidx,
    u16* __restrict__ outm, float* __restrict__ out_fwdw, int N, int E)
{
  const int g = threadIdx.x >> 5;
  const int l = threadIdx.x & 31;
  const int n = blockIdx.x * 8 + g;
  if (n >= N) return;
  const int beg = start[n], end = endp[n];

  float inv = 1.f;
  if (DIR == 0) {
    float sum = 0.f;
    for (int i = beg + l; i < end; i += 32) sum += pe[eidx[i]];
    for (int off = 16; off; off >>= 1) sum += __shfl_xor(sum, off, 32);
    inv = 1.f / (sum + 1e-9f);
    for (int i = beg + l; i < end; i += 32) {
      const int e = eidx[i];
      out_fwdw[e] = pe[e] * inv;
    }
  }

  float a0 = 0.f, a1 = 0.f, a2 = 0.f;
  for (int i = beg; i < end; ++i) {
    const int e = eidx[i];
    const float w = (DIR == 0) ? pe[e] * inv : revw[e];
    const int o = (DIR == 0) ? min(max(ei[e], 0), N - 1)
                             : min(max(ei[(size_t)E + e], 0), N - 1);
    const float* xr = x + (size_t)o * 96;
    a0 += w * xr[l];
    a1 += w * xr[l + 32];
    a2 += w * xr[l + 64];
  }
  u16* orow = outm + (size_t)n * 96;
  orow[l] = f2bf(a0); orow[l + 32] = f2bf(a1); orow[l + 64] = f2bf(a2);
}

// ===========================================================================
// Fused node kernel: 32 nodes/block, 4 waves. A = [x|fwdm|revm] bf16 in LDS
// (pure u32 copies). Three MLPs (reset, update, cand) run sequentially with
// register-resident weight fragments streamed from L2 (no Blds, no per-step
// barriers). r, z stay in registers (same thread owns same (row,col) in all
// epilogues); r*x applied in-place to Alds before the cand MLP. Final GRU
// update written directly.
// ===========================================================================
__device__ __forceinline__ void node_mlp(
    const u16* __restrict__ Alds, u16* __restrict__ Hlds,
    const bf16x8* __restrict__ W1f, const bf16x8* __restrict__ W2f,
    const float* __restrict__ b1,
    int wave, int lane, int q, int c, int ntc, int ntc2,
    f32x4 (&acc2)[2][2])
{
  f32x4 acc[2][5];
#pragma unroll
  for (int m = 0; m < 2; ++m)
    for (int t = 0; t < 5; ++t) acc[m][t] = (f32x4){0.f, 0.f, 0.f, 0.f};

#pragma unroll
  for (int kt = 0; kt < KT_G; ++kt) {
    const bf16x8 a0 = *(const bf16x8*)&Alds[c * NS + kt * 32 + q * 8];
    const bf16x8 a1 = *(const bf16x8*)&Alds[(16 + c) * NS + kt * 32 + q * 8];
#pragma unroll
    for (int t = 0; t < 5; ++t) {
      if (t < ntc) {
        const int nt = wave + 4 * t;
        const bf16x8 b = W1f[(kt * 18 + nt) * 64 + lane];
        acc[0][t] = mfma_bf16(a0, b, acc[0][t]);
        acc[1][t] = mfma_bf16(a1, b, acc[1][t]);
      }
    }
  }

  __syncthreads();                       // prior Hlds readers done
#pragma unroll
  for (int t = 0; t < 5; ++t) {
    if (t < ntc) {
      const int n = (wave + 4 * t) * 16 + c;
      const float b1f = b1[n];
#pragma unroll
      for (int m = 0; m < 2; ++m)
        for (int r = 0; r < 4; ++r) {
          float h = acc[m][t][r] + b1f;
          h = h > 0.f ? h : 0.f;
          Hlds[(m * 16 + q * 4 + r) * NS + n] = f2bf(h);
        }
    }
  }
  __syncthreads();                       // H complete

#pragma unroll
  for (int m = 0; m < 2; ++m)
    for (int t = 0; t < 2; ++t) acc2[m][t] = (f32x4){0.f, 0.f, 0.f, 0.f};
#pragma unroll
  for (int kt = 0; kt < KT_G; ++kt) {
    const bf16x8 a0 = *(const bf16x8*)&Hlds[c * NS + kt * 32 + q * 8];
    const bf16x8 a1 = *(const bf16x8*)&Hlds[(16 + c) * NS + kt * 32 + q * 8];
#pragma unroll
    for (int t = 0; t < 2; ++t) {
      if (t < ntc2) {
        const int nt = wave + 4 * t;
        const bf16x8 b = W2f[(kt * 6 + nt) * 64 + lane];
        acc2[0][t] = mfma_bf16(a0, b, acc2[0][t]);
        acc2[1][t] = mfma_bf16(a1, b, acc2[1][t]);
      }
    }
  }
}

__global__ __launch_bounds__(256) void node_fused(
    const float* __restrict__ x, const u32* __restrict__ xb,
    const u32* __restrict__ fwdmb, const u32* __restrict__ revmb,
    const uint4* __restrict__ NodeF,
    const float* __restrict__ b1r, const float* __restrict__ b2r,
    const float* __restrict__ b1u, const float* __restrict__ b2u,
    const float* __restrict__ b1c, const float* __restrict__ b2c,
    float* __restrict__ out_r, float* __restrict__ out_z,
    float* __restrict__ out_upd, int N)
{
  __shared__ __align__(16) u16 Alds[32 * NS];   // 18,944 B
  __shared__ __align__(16) u16 Hlds[32 * NS];   // 18,944 B

  const int tid = threadIdx.x;
  const int wave = tid >> 6, lane = tid & 63;
  const int q = lane >> 4, c = lane & 15;
  const int n0 = blockIdx.x * 32;
  const int ntc  = (wave < 2) ? 5 : 4;          // 18 N-tiles over 4 waves
  const int ntc2 = (wave < 2) ? 2 : 1;          // 6 N-tiles over 4 waves

  // ---- gather A: pure u32 copies (all sources pre-converted bf16) ----
  {
    u32* Aw = (u32*)Alds;
    const int nl = tid >> 3, sub = tid & 7;
    const int node = min(n0 + nl, N - 1);
    const u32* xr = xb    + (size_t)node * 48;
    const u32* fr = fwdmb + (size_t)node * 48;
    const u32* rr = revmb + (size_t)node * 48;
    for (int p = sub; p < 144; p += 8) {
      u32 v;
      if (p < 48)      v = xr[p];
      else if (p < 96) v = fr[p - 48];
      else             v = rr[p - 96];
      Aw[nl * (NS / 2) + p] = v;
    }
  }
  __syncthreads();

  const bf16x8* W1fr = (const bf16x8*)(NodeF);
  const bf16x8* W2fr = (const bf16x8*)(NodeF + W1F_Q);
  const bf16x8* W1fu = (const bf16x8*)(NodeF + W1F_Q + W2F_Q);
  const bf16x8* W2fu = (const bf16x8*)(NodeF + 2 * W1F_Q + W2F_Q);
  const bf16x8* W1fc = (const bf16x8*)(NodeF + 2 * (W1F_Q + W2F_Q));
  const bf16x8* W2fc = (const bf16x8*)(NodeF + 3 * W1F_Q + 2 * W2F_Q);

  f32x4 acc2[2][2];

  // ---- reset gate ----
  node_mlp(Alds, Hlds, W1fr, W2fr, b1r, wave, lane, q, c, ntc, ntc2, acc2);
  float r_reg[2][2][4];
#pragma unroll
  for (int t = 0; t < 2; ++t) {
    if (t < ntc2) {
      const int n2 = (wave + 4 * t) * 16 + c;
      const float b2f = b2r[n2];
#pragma unroll
      for (int m = 0; m < 2; ++m)
        for (int r = 0; r < 4; ++r) {
          const float v = acc2[m][t][r] + b2f;
          const float rv = 1.f / (1.f + __expf(-v));
          r_reg[t][m][r] = rv;
          const int node = n0 + m * 16 + q * 4 + r;
          if (node < N) out_r[(size_t)node * HDIM + n2] = rv;
        }
    }
  }

  // ---- update gate ----
  node_mlp(Alds, Hlds, W1fu, W2fu, b1u, wave, lane, q, c, ntc, ntc2, acc2);
  float z_reg[2][2][4];
#pragma unroll
  for (int t = 0; t < 2; ++t) {
    if (t < ntc2) {
      const int n2 = (wave + 4 * t) * 16 + c;
      const float b2f = b2u[n2];
#pragma unroll
      for (int m = 0; m < 2; ++m)
        for (int r = 0; r < 4; ++r) {
          const float v = acc2[m][t][r] + b2f;
          const float zv = 1.f / (1.f + __expf(-v));
          z_reg[t][m][r] = zv;
          const int node = n0 + m * 16 + q * 4 + r;
          if (node < N) out_z[(size_t)node * HDIM + n2] = zv;
        }
    }
  }

  // ---- apply r to the x-columns of A in place (disjoint coverage) ----
#pragma unroll
  for (int t = 0; t < 2; ++t) {
    if (t < ntc2) {
      const int n2 = (wave + 4 * t) * 16 + c;
#pragma unroll
      for (int m = 0; m < 2; ++m)
        for (int r = 0; r < 4; ++r) {
          const int row = m * 16 + q * 4 + r;
          const int idx = row * NS + n2;
          Alds[idx] = f2bf(bf2f(Alds[idx]) * r_reg[t][m][r]);
        }
    }
  }
  __syncthreads();                      // updates visible to cand L1

  // ---- candidate + GRU update ----
  node_mlp(Alds, Hlds, W1fc, W2fc, b1c, wave, lane, q, c, ntc, ntc2, acc2);
#pragma unroll
  for (int t = 0; t < 2; ++t) {
    if (t < ntc2) {
      const int n2 = (wave + 4 * t) * 16 + c;
      const float b2f = b2c[n2];
#pragma unroll
      for (int m = 0; m < 2; ++m)
        for (int r = 0; r < 4; ++r) {
          const int node = n0 + m * 16 + q * 4 + r;
          if (node < N) {
            const float v = acc2[m][t][r] + b2f;
            const float ct = tanhf(v);
            const float z = z_reg[t][m][r];
            const float xv = x[(size_t)node * HDIM + n2];
            out_upd[(size_t)node * HDIM + n2] = (1.f - z) * xv + z * ct;
          }
        }
    }
  }
}

__global__ void sentinel_kernel(float* out, int n, float val) {
  const int i = blockIdx.x * 256 + threadIdx.x;
  if (i < n) out[i] = val;
}

// ---------------------------------------------------------------------------
extern "C" void kernel_launch(void* const* d_in, const int* in_sizes, int n_in,
                              void* d_out, int out_size, void* d_ws, size_t ws_size,
                              hipStream_t stream) {
  const float* x  = (const float*)d_in[0];
  const float* xs = (const float*)d_in[1];
  const float* ef = (const float*)d_in[2];
  const int*   ei = (const int*)d_in[3];

  const int N = in_sizes[0] / HDIM;
  const int E = in_sizes[3] / 2;

  float* out = (float*)d_out;

  const int NB = (N + 255) / 256;      // scan blocks (<=1024 supported)

  const bool sizes_ok =
      n_in == 24 && NB <= 1024 &&
      in_sizes[0] == N * HDIM && in_sizes[1] == N * SDIM &&
      in_sizes[2] == E * FDIM && in_sizes[3] == 2 * E &&
      in_sizes[4] == WATT * KA && in_sizes[5] == WATT &&
      in_sizes[6] == WATT && in_sizes[7] == 1 &&
      in_sizes[12] == KG * KG && in_sizes[13] == KG &&
      in_sizes[14] == HDIM * KG && in_sizes[15] == HDIM &&
      out_size == 3 * N * HDIM + 2 * E;
  if (!sizes_ok) {
    sentinel_kernel<<<(out_size + 255) / 256, 256, 0, stream>>>(out, out_size, 777.0f);
    return;
  }

  // ws layout (u32 units):
  // pe[E] | Bfrag[NFRAG uint4] | NodeF[NODEF_Q uint4] | xb[N*48] | xsb[N*24]
  // | fwdmb[N*48] | revmb[N*48] | deg_d,deg_s,start_d,start_s,pos_d,pos_s[N ea]
  // | bsum_d,bsum_s[1024 ea] | eidx_d[E] | eidx_s[E]
  const size_t eA = ((size_t)E + 3) & ~(size_t)3;     // 16B-align after pe
  const size_t needed =
      (eA + (size_t)NFRAG * 4 + (size_t)NODEF_Q * 4 +
       (size_t)N * 48 + (size_t)N * 24 + 2 * (size_t)N * 48 +
       6 * (size_t)N + 2048 + 2 * (size_t)E) * 4;
  if (ws_size < needed) {
    sentinel_kernel<<<(out_size + 255) / 256, 256, 0, stream>>>(out, out_size, 12345.0f);
    return;
  }
  float* pe    = (float*)d_ws;
  uint4* Bfrag = (uint4*)((u32*)d_ws + eA);
  uint4* NodeF = Bfrag + NFRAG;
  u32*   xbw   = (u32*)(NodeF + NODEF_Q);
  u32*   xsbw  = xbw + (size_t)N * 48;
  u32*   fwdmb = xsbw + (size_t)N * 24;
  u32*   revmb = fwdmb + (size_t)N * 48;
  int* deg_d   = (int*)(revmb + (size_t)N * 48);
  int* deg_s   = deg_d + N;
  int* start_d = deg_s + N;
  int* start_s = start_d + N;
  int* pos_d   = start_s + N;
  int* pos_s   = pos_d + N;
  int* bsum_d  = pos_s + N;
  int* bsum_s  = bsum_d + 1024;
  int* eidx_d  = bsum_s + 1024;
  int* eidx_s  = eidx_d + E;

  float* out_update = out;                         // [N,96]
  float* out_fwdw   = out + (size_t)N * HDIM;      // [E]
  float* out_revw   = out_fwdw + E;                // [E]
  float* out_z      = out_revw + E;                // [N,96]
  float* out_r      = out_z + (size_t)N * HDIM;    // [N,96]

  (void)hipMemsetAsync(deg_d, 0, 2 * (size_t)N * sizeof(int), stream);

  // weight + activation prep
  w_prep<<<(NFRAG + 255) / 256, 256, 0, stream>>>(
      (const float*)d_in[4], (const float*)d_in[8], Bfrag);
  const int g1 = (KT_G * 18 * 64 + 255) / 256;
  const int g2 = (KT_G * 6 * 64 + 255) / 256;
  w_prep_node<<<g1, 256, 0, stream>>>((const float*)d_in[12], NodeF, 18);
  w_prep_node<<<g2, 256, 0, stream>>>((const float*)d_in[14], NodeF + W1F_Q, 6);
  w_prep_node<<<g1, 256, 0, stream>>>((const float*)d_in[16],
                                      NodeF + W1F_Q + W2F_Q, 18);
  w_prep_node<<<g2, 256, 0, stream>>>((const float*)d_in[18],
                                      NodeF + 2 * W1F_Q + W2F_Q, 6);
  w_prep_node<<<g1, 256, 0, stream>>>((const float*)d_in[20],
                                      NodeF + 2 * (W1F_Q + W2F_Q), 18);
  w_prep_node<<<g2, 256, 0, stream>>>((const float*)d_in[22],
                                      NodeF + 3 * W1F_Q + 2 * W2F_Q, 6);
  x_prep<<<(N * 72 + 255) / 256, 256, 0, stream>>>(x, xs, xbw, xsbw, N);

  // CSR build
  const int eblk = (E + 255) / 256;
  k_hist<<<eblk, 256, 0, stream>>>(ei, deg_d, deg_s, N, E);
  k_scan1<<<NB, 256, 0, stream>>>(deg_d, deg_s, start_d, start_s,
                                  bsum_d, bsum_s, N);
  k_scan2<<<1, 64, 0, stream>>>(bsum_d, bsum_s, NB);
  k_scan3<<<NB, 256, 0, stream>>>(start_d, start_s, bsum_d, bsum_s,
                                  pos_d, pos_s, N);
  k_fill<<<eblk, 256, 0, stream>>>(ei, pos_d, pos_s, eidx_d, eidx_s, N, E);

  // edge MLPs
  edge_kernel<<<(E + 63) / 64, 256, 0, stream>>>(
      xbw, xsbw, ef, ei, (const u16*)Bfrag,
      (const float*)d_in[5], (const float*)d_in[6], (const float*)d_in[7],
      (const float*)d_in[9], (const float*)d_in[10], (const float*)d_in[11],
      pe, out_revw, N, E);

  // gather-aggregate -> bf16 message rows
  const int ablk = (N + 7) / 8;
  k_agg<0><<<ablk, 256, 0, stream>>>(x, ei, pe, out_revw, start_d, pos_d,
                                     eidx_d, (u16*)fwdmb, out_fwdw, N, E);
  k_agg<1><<<ablk, 256, 0, stream>>>(x, ei, pe, out_revw, start_s, pos_s,
                                     eidx_s, (u16*)revmb, out_fwdw, N, E);

  // fused node MLPs (reset + update + candidate + GRU)
  const int nblk = (N + 31) / 32;
  node_fused<<<nblk, 256, 0, stream>>>(
      x, xbw, fwdmb, revmb, NodeF,
      (const float*)d_in[13], (const float*)d_in[15],
      (const float*)d_in[17], (const float*)d_in[19],
      (const float*)d_in[21], (const float*)d_in[23],
      out_r, out_z, out_update, N);
}

// Round 4
// 1131.052 us; speedup vs baseline: 3.7378x; 1.0293x over previous
//
#include <hip/hip_runtime.h>
#include <math.h>

typedef unsigned short u16;
typedef unsigned int   u32;

#define HDIM 96
#define SDIM 48
#define FDIM 24
#define KA   312      // 2H + 2S + F
#define WATT 192
#define KG   288      // 3H

// edge MFMA tiling
#define AS_E  328     // edge A LDS row stride in u16 (656 B = 41 uint4)
#define KT_A  10      // K-steps of 32 (K padded 312 -> 320)
#define KT_G  9       // node K-steps (288)
#define NS    296     // node LDS row stride in u16 (592 B = 37 uint4)

#define NFRAG (2 * KT_A * 12 * 64)   // edge W1 fragments (uint4 count)
#define W1F_Q (KT_G * 18 * 64)       // 10368 uint4 per node W1
#define W2F_Q (KT_G * 6 * 64)        //  3456 uint4 per node W2
#define NODEF_Q (3 * (W1F_Q + W2F_Q))

typedef __attribute__((ext_vector_type(8))) __bf16 bf16x8;
typedef __attribute__((ext_vector_type(4))) float  f32x4;

__device__ __forceinline__ u16 f2bf(float f) {
  u32 u = __float_as_uint(f);
  u = (u + 0x7FFFu + ((u >> 16) & 1u)) >> 16;   // RNE
  return (u16)u;
}
__device__ __forceinline__ float bf2f(u16 v) {
  return __uint_as_float((u32)v << 16);
}
__device__ __forceinline__ u32 pack2(float a, float b) {
  return (u32)f2bf(a) | ((u32)f2bf(b) << 16);
}
__device__ __forceinline__ f32x4 mfma_bf16(bf16x8 a, bf16x8 b, f32x4 c) {
  return __builtin_amdgcn_mfma_f32_16x16x32_bf16(a, b, c, 0, 0, 0);
}

// ===========================================================================
// Edge W1 prep: fp32 [192x312] -> bf16 fragments, rev input-permutation
// folded in, K padded 312->320.
// ===========================================================================
__global__ __launch_bounds__(256) void w_prep(
    const float* __restrict__ fW1, const float* __restrict__ rW1,
    uint4* __restrict__ Bfrag)
{
  const int idx = blockIdx.x * 256 + threadIdx.x;
  if (idx >= NFRAG) return;
  const int lane = idx & 63;
  const int frag = idx >> 6;
  const int nt   = frag % 12;
  const int rest = frag / 12;
  const int kt   = rest % KT_A;
  const int mlp  = rest / KT_A;
  const int q = lane >> 4, c = lane & 15;
  const int n  = nt * 16 + c;
  const int p0 = kt * 16 + q * 4;
  const float* W = mlp ? rW1 : fW1;
  u32 v[4];
#pragma unroll
  for (int w = 0; w < 4; ++w) {
    const int p = p0 + w;
    u32 val = 0u;
    if (p < 156) {
      int src = p;
      if (mlp) {
        if (src < 48)       src += 48;
        else if (src < 96)  src -= 48;
        else if (src < 120) src += 24;
        else if (src < 144) src -= 24;
      }
      const float2 wv = *(const float2*)(W + (size_t)n * KA + 2 * src);
      val = pack2(wv.x, wv.y);
    }
    v[w] = val;
  }
  Bfrag[idx] = make_uint4(v[0], v[1], v[2], v[3]);
}

// ===========================================================================
// Node weight prep: W [NT*16 x 288] fp32 -> bf16 fragments [kt][nt][lane].
// ===========================================================================
__global__ __launch_bounds__(256) void w_prep_node(
    const float* __restrict__ W, uint4* __restrict__ outf, int NT)
{
  const int nfrag = KT_G * NT * 64;
  const int idx = blockIdx.x * 256 + threadIdx.x;
  if (idx >= nfrag) return;
  const int lane = idx & 63;
  const int frag = idx >> 6;
  const int nt = frag % NT, kt = frag / NT;
  const int q = lane >> 4, c = lane & 15;
  const int n = nt * 16 + c;
  const int k0 = kt * 32 + q * 8;
  u32 v[4];
#pragma unroll
  for (int w = 0; w < 4; ++w) {
    const float2 wv = *(const float2*)(W + (size_t)n * KG + k0 + 2 * w);
    v[w] = pack2(wv.x, wv.y);
  }
  outf[idx] = make_uint4(v[0], v[1], v[2], v[3]);
}

// ===========================================================================
// Activation prep: x [N x 96] and xs [N x 48] fp32 -> bf16 (packed pairs).
// ===========================================================================
__global__ __launch_bounds__(256) void x_prep(
    const float* __restrict__ x, const float* __restrict__ xs,
    u32* __restrict__ xb, u32* __restrict__ xsb, int N)
{
  const int i = blockIdx.x * 256 + threadIdx.x;
  const int nx = N * 48;
  if (i < nx) {
    const float2 v = ((const float2*)x)[i];
    xb[i] = pack2(v.x, v.y);
  } else if (i < nx + N * 24) {
    const float2 v = ((const float2*)xs)[i - nx];
    xsb[i - nx] = pack2(v.x, v.y);
  }
}

// ===========================================================================
// Edge kernel: 64 edges/block, 4 waves. Gather is now a STATIC per-sub
// uint4 burst: each of the 4 threads/edge owns a fixed 10-uint4 chunk of
// the 40-uint4 feature row; all 10 loads issue before any LDS write (one
// latency exposure instead of 40). K-loop: register-resident W1 fragments
// (barrier-free). Epilogue -> pe / out_revw.
// ===========================================================================
__global__ __launch_bounds__(256, 2) void edge_kernel(
    const u32* __restrict__ xb, const u32* __restrict__ xsb,
    const float* __restrict__ ef, const int* __restrict__ ei,
    const u16* __restrict__ Bfrag,
    const float* __restrict__ fb1, const float* __restrict__ fW2,
    const float* __restrict__ fb2,
    const float* __restrict__ rb1, const float* __restrict__ rW2,
    const float* __restrict__ rb2,
    float* __restrict__ pe, float* __restrict__ out_revw, int N, int E)
{
  __shared__ __align__(16) u16 Alds[64 * AS_E];   // 41,984 B
  __shared__ float red[4][64];

  const int tid  = threadIdx.x;
  const int wave = tid >> 6, lane = tid & 63;
  const int q = lane >> 4, c = lane & 15;
  const int e0 = blockIdx.x * 64;

  // ---- gather A: static uint4 chunks (u4 index map: x[s]=0..11,
  //      x[d]=12..23, xs[s]=24..29, xs[d]=30..35, ef=36..38, pad=39) ----
  {
    const int el = tid >> 2, sub = tid & 3;
    const int e = min(e0 + el, E - 1);
    int s = ei[e], d = ei[(size_t)E + e];
    s = min(max(s, 0), N - 1); d = min(max(d, 0), N - 1);
    const uint4* xsr = (const uint4*)(xb  + (size_t)s * 48);   // 12 u4
    const uint4* xdr = (const uint4*)(xb  + (size_t)d * 48);   // 12 u4
    const uint4* ssr = (const uint4*)(xsb + (size_t)s * 24);   //  6 u4
    const uint4* sdr = (const uint4*)(xsb + (size_t)d * 24);   //  6 u4
    uint4* Arow = (uint4*)&Alds[el * AS_E];                    // 41 u4/row
    uint4 v[10];
    if (sub == 0) {
#pragma unroll
      for (int i = 0; i < 10; ++i) v[i] = xsr[i];
    } else if (sub == 1) {
      v[0] = xsr[10]; v[1] = xsr[11];
#pragma unroll
      for (int i = 0; i < 8; ++i) v[2 + i] = xdr[i];
    } else if (sub == 2) {
#pragma unroll
      for (int i = 0; i < 4; ++i) v[i] = xdr[8 + i];
#pragma unroll
      for (int i = 0; i < 6; ++i) v[4 + i] = ssr[i];
    } else {
#pragma unroll
      for (int i = 0; i < 6; ++i) v[i] = sdr[i];
      const float4* efr = (const float4*)(ef + (size_t)e * 24);
#pragma unroll
      for (int u = 0; u < 3; ++u) {
        const float4 a = efr[2 * u], b = efr[2 * u + 1];
        v[6 + u] = make_uint4(pack2(a.x, a.y), pack2(a.z, a.w),
                              pack2(b.x, b.y), pack2(b.z, b.w));
      }
      v[9] = make_uint4(0u, 0u, 0u, 0u);
    }
#pragma unroll
    for (int i = 0; i < 10; ++i) Arow[sub * 10 + i] = v[i];
  }
  __syncthreads();                                // A ready (read-only after)

  const bf16x8* __restrict__ Bf = (const bf16x8*)Bfrag;

  for (int mlp = 0; mlp < 2; ++mlp) {
    f32x4 acc[4][3];
#pragma unroll
    for (int m = 0; m < 4; ++m)
      for (int t = 0; t < 3; ++t)
        acc[m][t] = (f32x4){0.f, 0.f, 0.f, 0.f};

#pragma unroll
    for (int kt = 0; kt < KT_A; ++kt) {
      bf16x8 a[4];
#pragma unroll
      for (int m = 0; m < 4; ++m)
        a[m] = *(const bf16x8*)&Alds[(m * 16 + c) * AS_E + kt * 32 + q * 8];
#pragma unroll
      for (int t = 0; t < 3; ++t) {
        const bf16x8 b =
            Bf[(((mlp * KT_A + kt) * 12) + wave * 3 + t) * 64 + lane];
#pragma unroll
        for (int m = 0; m < 4; ++m)
          acc[m][t] = mfma_bf16(a[m], b, acc[m][t]);
      }
    }

    // ---- epilogue: bias + relu + dot(W2), reduce across 16 col-lanes ----
    const float* b1p = mlp ? rb1 : fb1;
    const float* W2p = mlp ? rW2 : fW2;
    float p[4][4];
#pragma unroll
    for (int m = 0; m < 4; ++m)
      for (int r = 0; r < 4; ++r) p[m][r] = 0.f;
#pragma unroll
    for (int t = 0; t < 3; ++t) {
      const int n = (wave * 3 + t) * 16 + c;
      const float b1f = b1p[n];
      const float w2f = W2p[n];
#pragma unroll
      for (int m = 0; m < 4; ++m)
        for (int r = 0; r < 4; ++r) {
          float h = acc[m][t][r] + b1f;
          h = h > 0.f ? h : 0.f;
          p[m][r] += h * w2f;
        }
    }
    for (int off = 1; off <= 8; off <<= 1)
#pragma unroll
      for (int m = 0; m < 4; ++m)
        for (int r = 0; r < 4; ++r)
          p[m][r] += __shfl_xor(p[m][r], off, 64);

    __syncthreads();
    if (c == 0) {
#pragma unroll
      for (int m = 0; m < 4; ++m)
        for (int r = 0; r < 4; ++r)
          red[wave][m * 16 + q * 4 + r] = p[m][r];
    }
    __syncthreads();

    if (tid < 64 && e0 + tid < E) {
      float raw = red[0][tid] + red[1][tid] + red[2][tid] + red[3][tid];
      const int e = e0 + tid;
      if (mlp == 0) {
        raw += fb2[0];
        const float lr = raw > 0.f ? raw : 0.01f * raw;      // leaky_relu
        pe[e] = __expf(lr * 0.10206207261596575f);           // /sqrt(96)
      } else {
        raw += rb2[0];
        out_revw[e] = 1.f / (1.f + __expf(-raw));
      }
    }
  }
}

// ===========================================================================
// CSR build (unchanged).
// ===========================================================================
__global__ __launch_bounds__(256) void k_hist(
    const int* __restrict__ ei, int* __restrict__ deg_d,
    int* __restrict__ deg_s, int N, int E)
{
  const int e = blockIdx.x * 256 + threadIdx.x;
  if (e >= E) return;
  const int s = min(max(ei[e], 0), N - 1);
  const int d = min(max(ei[(size_t)E + e], 0), N - 1);
  atomicAdd(&deg_d[d], 1);
  atomicAdd(&deg_s[s], 1);
}

__global__ __launch_bounds__(256) void k_scan1(
    const int* __restrict__ deg_d, const int* __restrict__ deg_s,
    int* __restrict__ start_d, int* __restrict__ start_s,
    int* __restrict__ bsum_d, int* __restrict__ bsum_s, int N)
{
  __shared__ int sh[256];
  const int t = threadIdx.x, i = blockIdx.x * 256 + t;
  {
    const int v = (i < N) ? deg_d[i] : 0;
    sh[t] = v; __syncthreads();
    for (int off = 1; off < 256; off <<= 1) {
      const int u = (t >= off) ? sh[t - off] : 0;
      __syncthreads();
      sh[t] += u;
      __syncthreads();
    }
    if (i < N) start_d[i] = sh[t] - v;
    if (t == 255) bsum_d[blockIdx.x] = sh[255];
    __syncthreads();
  }
  {
    const int v = (i < N) ? deg_s[i] : 0;
    sh[t] = v; __syncthreads();
    for (int off = 1; off < 256; off <<= 1) {
      const int u = (t >= off) ? sh[t - off] : 0;
      __syncthreads();
      sh[t] += u;
      __syncthreads();
    }
    if (i < N) start_s[i] = sh[t] - v;
    if (t == 255) bsum_s[blockIdx.x] = sh[255];
  }
}

__global__ void k_scan2(int* bsum_d, int* bsum_s, int nb) {
  if (threadIdx.x == 0) {
    int r = 0;
    for (int b = 0; b < nb; ++b) { const int t = bsum_d[b]; bsum_d[b] = r; r += t; }
  } else if (threadIdx.x == 1) {
    int r = 0;
    for (int b = 0; b < nb; ++b) { const int t = bsum_s[b]; bsum_s[b] = r; r += t; }
  }
}

__global__ __launch_bounds__(256) void k_scan3(
    int* __restrict__ start_d, int* __restrict__ start_s,
    const int* __restrict__ bsum_d, const int* __restrict__ bsum_s,
    int* __restrict__ pos_d, int* __restrict__ pos_s, int N)
{
  const int i = blockIdx.x * 256 + threadIdx.x;
  if (i >= N) return;
  const int b = i >> 8;
  const int vd = start_d[i] + bsum_d[b]; start_d[i] = vd; pos_d[i] = vd;
  const int vs = start_s[i] + bsum_s[b]; start_s[i] = vs; pos_s[i] = vs;
}

__global__ __launch_bounds__(256) void k_fill(
    const int* __restrict__ ei, int* __restrict__ pos_d,
    int* __restrict__ pos_s, int* __restrict__ eidx_d,
    int* __restrict__ eidx_s, int N, int E)
{
  const int e = blockIdx.x * 256 + threadIdx.x;
  if (e >= E) return;
  const int s = min(max(ei[e], 0), N - 1);
  const int d = min(max(ei[(size_t)E + e], 0), N - 1);
  eidx_d[atomicAdd(&pos_d[d], 1)] = e;
  eidx_s[atomicAdd(&pos_s[s], 1)] = e;
}

// ===========================================================================
// Gather-aggregate (unchanged): 32-lane group per node, bf16 row output.
// ===========================================================================
template <int DIR>
__global__ __launch_bounds__(256) void k_agg(
    const float* __restrict__ x, const int* __restrict__ ei,
    const float* __restrict__ pe, const float* __restrict__ revw,
    const int* __restrict__ start, const int* __restrict__ endp,
    const int* __restrict__ eidx,
    u16* __restrict__ outm, float* __restrict__ out_fwdw, int N, int E)
{
  const int g = threadIdx.x >> 5;
  const int l = threadIdx.x & 31;
  const int n = blockIdx.x * 8 + g;
  if (n >= N) return;
  const int beg = start[n], end = endp[n];

  float inv = 1.f;
  if (DIR == 0) {
    float sum = 0.f;
    for (int i = beg + l; i < end; i += 32) sum += pe[eidx[i]];
    for (int off = 16; off; off >>= 1) sum += __shfl_xor(sum, off, 32);
    inv = 1.f / (sum + 1e-9f);
    for (int i = beg + l; i < end; i += 32) {
      const int e = eidx[i];
      out_fwdw[e] = pe[e] * inv;
    }
  }

  float a0 = 0.f, a1 = 0.f, a2 = 0.f;
  for (int i = beg; i < end; ++i) {
    const int e = eidx[i];
    const float w = (DIR == 0) ? pe[e] * inv : revw[e];
    const int o = (DIR == 0) ? min(max(ei[e], 0), N - 1)
                             : min(max(ei[(size_t)E + e], 0), N - 1);
    const float* xr = x + (size_t)o * 96;
    a0 += w * xr[l];
    a1 += w * xr[l + 32];
    a2 += w * xr[l + 64];
  }
  u16* orow = outm + (size_t)n * 96;
  orow[l] = f2bf(a0); orow[l + 32] = f2bf(a1); orow[l + 64] = f2bf(a2);
}

// ===========================================================================
// Fused node kernel v2: 64 nodes/block, 256 threads (4 waves), M-tiles=4.
// A = [x|fwdm|revm] bf16 in LDS (static uint4 burst gather). Three MLPs
// sequential with register-resident weight fragments streamed from L2.
// r,z in registers; r*x applied in-place to Alds; GRU update fused.
// ===========================================================================
__device__ __forceinline__ void node_mlp(
    const u16* __restrict__ Alds, u16* __restrict__ Hlds,
    const bf16x8* __restrict__ W1f, const bf16x8* __restrict__ W2f,
    const float* __restrict__ b1,
    int wave, int lane, int q, int c, int ntc, int ntc2,
    f32x4 (&acc2)[4][2])
{
  f32x4 acc[4][5];
#pragma unroll
  for (int m = 0; m < 4; ++m)
    for (int t = 0; t < 5; ++t) acc[m][t] = (f32x4){0.f, 0.f, 0.f, 0.f};

#pragma unroll
  for (int kt = 0; kt < KT_G; ++kt) {
    bf16x8 a[4];
#pragma unroll
    for (int m = 0; m < 4; ++m)
      a[m] = *(const bf16x8*)&Alds[(m * 16 + c) * NS + kt * 32 + q * 8];
#pragma unroll
    for (int t = 0; t < 5; ++t) {
      if (t < ntc) {
        const int nt = wave + 4 * t;
        const bf16x8 b = W1f[(kt * 18 + nt) * 64 + lane];
#pragma unroll
        for (int m = 0; m < 4; ++m)
          acc[m][t] = mfma_bf16(a[m], b, acc[m][t]);
      }
    }
  }

  __syncthreads();                       // prior Hlds readers done
#pragma unroll
  for (int t = 0; t < 5; ++t) {
    if (t < ntc) {
      const int n = (wave + 4 * t) * 16 + c;
      const float b1f = b1[n];
#pragma unroll
      for (int m = 0; m < 4; ++m)
        for (int r = 0; r < 4; ++r) {
          float h = acc[m][t][r] + b1f;
          h = h > 0.f ? h : 0.f;
          Hlds[(m * 16 + q * 4 + r) * NS + n] = f2bf(h);
        }
    }
  }
  __syncthreads();                       // H complete

#pragma unroll
  for (int m = 0; m < 4; ++m)
    for (int t = 0; t < 2; ++t) acc2[m][t] = (f32x4){0.f, 0.f, 0.f, 0.f};
#pragma unroll
  for (int kt = 0; kt < KT_G; ++kt) {
    bf16x8 a[4];
#pragma unroll
    for (int m = 0; m < 4; ++m)
      a[m] = *(const bf16x8*)&Hlds[(m * 16 + c) * NS + kt * 32 + q * 8];
#pragma unroll
    for (int t = 0; t < 2; ++t) {
      if (t < ntc2) {
        const int nt = wave + 4 * t;
        const bf16x8 b = W2f[(kt * 6 + nt) * 64 + lane];
#pragma unroll
        for (int m = 0; m < 4; ++m)
          acc2[m][t] = mfma_bf16(a[m], b, acc2[m][t]);
      }
    }
  }
}

__global__ __launch_bounds__(256, 2) void node_fused(
    const float* __restrict__ x, const u32* __restrict__ xb,
    const u32* __restrict__ fwdmb, const u32* __restrict__ revmb,
    const uint4* __restrict__ NodeF,
    const float* __restrict__ b1r, const float* __restrict__ b2r,
    const float* __restrict__ b1u, const float* __restrict__ b2u,
    const float* __restrict__ b1c, const float* __restrict__ b2c,
    float* __restrict__ out_r, float* __restrict__ out_z,
    float* __restrict__ out_upd, int N)
{
  __shared__ __align__(16) u16 Alds[64 * NS];   // 37,888 B
  __shared__ __align__(16) u16 Hlds[64 * NS];   // 37,888 B

  const int tid = threadIdx.x;
  const int wave = tid >> 6, lane = tid & 63;
  const int q = lane >> 4, c = lane & 15;
  const int n0 = blockIdx.x * 64;
  const int ntc  = (wave < 2) ? 5 : 4;          // 18 N-tiles over 4 waves
  const int ntc2 = (wave < 2) ? 2 : 1;          // 6 N-tiles over 4 waves

  // ---- gather A: static uint4 chunks (u4 map: x=0..11, f=12..23, r=24..35)
  {
    const int nl = tid >> 2, sub = tid & 3;
    const int node = min(n0 + nl, N - 1);
    const uint4* xr = (const uint4*)(xb    + (size_t)node * 48);
    const uint4* fr = (const uint4*)(fwdmb + (size_t)node * 48);
    const uint4* rr = (const uint4*)(revmb + (size_t)node * 48);
    uint4* Arow = (uint4*)&Alds[nl * NS];       // 37 u4/row
    uint4 v[9];
    if (sub == 0) {
#pragma unroll
      for (int i = 0; i < 9; ++i) v[i] = xr[i];
    } else if (sub == 1) {
      v[0] = xr[9]; v[1] = xr[10]; v[2] = xr[11];
#pragma unroll
      for (int i = 0; i < 6; ++i) v[3 + i] = fr[i];
    } else if (sub == 2) {
#pragma unroll
      for (int i = 0; i < 6; ++i) v[i] = fr[6 + i];
      v[6] = rr[0]; v[7] = rr[1]; v[8] = rr[2];
    } else {
#pragma unroll
      for (int i = 0; i < 9; ++i) v[i] = rr[3 + i];
    }
#pragma unroll
    for (int i = 0; i < 9; ++i) Arow[sub * 9 + i] = v[i];
  }
  __syncthreads();

  const bf16x8* W1fr = (const bf16x8*)(NodeF);
  const bf16x8* W2fr = (const bf16x8*)(NodeF + W1F_Q);
  const bf16x8* W1fu = (const bf16x8*)(NodeF + W1F_Q + W2F_Q);
  const bf16x8* W2fu = (const bf16x8*)(NodeF + 2 * W1F_Q + W2F_Q);
  const bf16x8* W1fc = (const bf16x8*)(NodeF + 2 * (W1F_Q + W2F_Q));
  const bf16x8* W2fc = (const bf16x8*)(NodeF + 3 * W1F_Q + 2 * W2F_Q);

  f32x4 acc2[4][2];

  // ---- reset gate ----
  node_mlp(Alds, Hlds, W1fr, W2fr, b1r, wave, lane, q, c, ntc, ntc2, acc2);
  float r_reg[2][4][4];
#pragma unroll
  for (int t = 0; t < 2; ++t) {
    if (t < ntc2) {
      const int n2 = (wave + 4 * t) * 16 + c;
      const float b2f = b2r[n2];
#pragma unroll
      for (int m = 0; m < 4; ++m)
        for (int r = 0; r < 4; ++r) {
          const float v = acc2[m][t][r] + b2f;
          const float rv = 1.f / (1.f + __expf(-v));
          r_reg[t][m][r] = rv;
          const int node = n0 + m * 16 + q * 4 + r;
          if (node < N) out_r[(size_t)node * HDIM + n2] = rv;
        }
    }
  }

  // ---- update gate ----
  node_mlp(Alds, Hlds, W1fu, W2fu, b1u, wave, lane, q, c, ntc, ntc2, acc2);
  float z_reg[2][4][4];
#pragma unroll
  for (int t = 0; t < 2; ++t) {
    if (t < ntc2) {
      const int n2 = (wave + 4 * t) * 16 + c;
      const float b2f = b2u[n2];
#pragma unroll
      for (int m = 0; m < 4; ++m)
        for (int r = 0; r < 4; ++r) {
          const float v = acc2[m][t][r] + b2f;
          const float zv = 1.f / (1.f + __expf(-v));
          z_reg[t][m][r] = zv;
          const int node = n0 + m * 16 + q * 4 + r;
          if (node < N) out_z[(size_t)node * HDIM + n2] = zv;
        }
    }
  }

  // ---- apply r to the x-columns of A in place (disjoint coverage) ----
#pragma unroll
  for (int t = 0; t < 2; ++t) {
    if (t < ntc2) {
      const int n2 = (wave + 4 * t) * 16 + c;
#pragma unroll
      for (int m = 0; m < 4; ++m)
        for (int r = 0; r < 4; ++r) {
          const int row = m * 16 + q * 4 + r;
          const int idx = row * NS + n2;
          Alds[idx] = f2bf(bf2f(Alds[idx]) * r_reg[t][m][r]);
        }
    }
  }
  __syncthreads();                      // updates visible to cand L1

  // ---- candidate + GRU update ----
  node_mlp(Alds, Hlds, W1fc, W2fc, b1c, wave, lane, q, c, ntc, ntc2, acc2);
#pragma unroll
  for (int t = 0; t < 2; ++t) {
    if (t < ntc2) {
      const int n2 = (wave + 4 * t) * 16 + c;
      const float b2f = b2c[n2];
#pragma unroll
      for (int m = 0; m < 4; ++m)
        for (int r = 0; r < 4; ++r) {
          const int node = n0 + m * 16 + q * 4 + r;
          if (node < N) {
            const float v = acc2[m][t][r] + b2f;
            const float ct = tanhf(v);
            const float z = z_reg[t][m][r];
            const float xv = x[(size_t)node * HDIM + n2];
            out_upd[(size_t)node * HDIM + n2] = (1.f - z) * xv + z * ct;
          }
        }
    }
  }
}

__global__ void sentinel_kernel(float* out, int n, float val) {
  const int i = blockIdx.x * 256 + threadIdx.x;
  if (i < n) out[i] = val;
}

// ---------------------------------------------------------------------------
extern "C" void kernel_launch(void* const* d_in, const int* in_sizes, int n_in,
                              void* d_out, int out_size, void* d_ws, size_t ws_size,
                              hipStream_t stream) {
  const float* x  = (const float*)d_in[0];
  const float* xs = (const float*)d_in[1];
  const float* ef = (const float*)d_in[2];
  const int*   ei = (const int*)d_in[3];

  const int N = in_sizes[0] / HDIM;
  const int E = in_sizes[3] / 2;

  float* out = (float*)d_out;

  const int NB = (N + 255) / 256;      // scan blocks (<=1024 supported)

  const bool sizes_ok =
      n_in == 24 && NB <= 1024 &&
      in_sizes[0] == N * HDIM && in_sizes[1] == N * SDIM &&
      in_sizes[2] == E * FDIM && in_sizes[3] == 2 * E &&
      in_sizes[4] == WATT * KA && in_sizes[5] == WATT &&
      in_sizes[6] == WATT && in_sizes[7] == 1 &&
      in_sizes[12] == KG * KG && in_sizes[13] == KG &&
      in_sizes[14] == HDIM * KG && in_sizes[15] == HDIM &&
      out_size == 3 * N * HDIM + 2 * E;
  if (!sizes_ok) {
    sentinel_kernel<<<(out_size + 255) / 256, 256, 0, stream>>>(out, out_size, 777.0f);
    return;
  }

  // ws layout (u32 units):
  // pe[E] | Bfrag[NFRAG uint4] | NodeF[NODEF_Q uint4] | xb[N*48] | xsb[N*24]
  // | fwdmb[N*48] | revmb[N*48] | deg_d,deg_s,start_d,start_s,pos_d,pos_s[N]
  // | bsum_d,bsum_s[1024 ea] | eidx_d[E] | eidx_s[E]
  const size_t eA = ((size_t)E + 3) & ~(size_t)3;     // 16B-align after pe
  const size_t needed =
      (eA + (size_t)NFRAG * 4 + (size_t)NODEF_Q * 4 +
       (size_t)N * 48 + (size_t)N * 24 + 2 * (size_t)N * 48 +
       6 * (size_t)N + 2048 + 2 * (size_t)E) * 4;
  if (ws_size < needed) {
    sentinel_kernel<<<(out_size + 255) / 256, 256, 0, stream>>>(out, out_size, 12345.0f);
    return;
  }
  float* pe    = (float*)d_ws;
  uint4* Bfrag = (uint4*)((u32*)d_ws + eA);
  uint4* NodeF = Bfrag + NFRAG;
  u32*   xbw   = (u32*)(NodeF + NODEF_Q);
  u32*   xsbw  = xbw + (size_t)N * 48;
  u32*   fwdmb = xsbw + (size_t)N * 24;
  u32*   revmb = fwdmb + (size_t)N * 48;
  int* deg_d   = (int*)(revmb + (size_t)N * 48);
  int* deg_s   = deg_d + N;
  int* start_d = deg_s + N;
  int* start_s = start_d + N;
  int* pos_d   = start_s + N;
  int* pos_s   = pos_d + N;
  int* bsum_d  = pos_s + N;
  int* bsum_s  = bsum_d + 1024;
  int* eidx_d  = bsum_s + 1024;
  int* eidx_s  = eidx_d + E;

  float* out_update = out;                         // [N,96]
  float* out_fwdw   = out + (size_t)N * HDIM;      // [E]
  float* out_revw   = out_fwdw + E;                // [E]
  float* out_z      = out_revw + E;                // [N,96]
  float* out_r      = out_z + (size_t)N * HDIM;    // [N,96]

  (void)hipMemsetAsync(deg_d, 0, 2 * (size_t)N * sizeof(int), stream);

  // weight + activation prep
  w_prep<<<(NFRAG + 255) / 256, 256, 0, stream>>>(
      (const float*)d_in[4], (const float*)d_in[8], Bfrag);
  const int g1 = (KT_G * 18 * 64 + 255) / 256;
  const int g2 = (KT_G * 6 * 64 + 255) / 256;
  w_prep_node<<<g1, 256, 0, stream>>>((const float*)d_in[12], NodeF, 18);
  w_prep_node<<<g2, 256, 0, stream>>>((const float*)d_in[14], NodeF + W1F_Q, 6);
  w_prep_node<<<g1, 256, 0, stream>>>((const float*)d_in[16],
                                      NodeF + W1F_Q + W2F_Q, 18);
  w_prep_node<<<g2, 256, 0, stream>>>((const float*)d_in[18],
                                      NodeF + 2 * W1F_Q + W2F_Q, 6);
  w_prep_node<<<g1, 256, 0, stream>>>((const float*)d_in[20],
                                      NodeF + 2 * (W1F_Q + W2F_Q), 18);
  w_prep_node<<<g2, 256, 0, stream>>>((const float*)d_in[22],
                                      NodeF + 3 * W1F_Q + 2 * W2F_Q, 6);
  x_prep<<<(N * 72 + 255) / 256, 256, 0, stream>>>(x, xs, xbw, xsbw, N);

  // CSR build
  const int eblk = (E + 255) / 256;
  k_hist<<<eblk, 256, 0, stream>>>(ei, deg_d, deg_s, N, E);
  k_scan1<<<NB, 256, 0, stream>>>(deg_d, deg_s, start_d, start_s,
                                  bsum_d, bsum_s, N);
  k_scan2<<<1, 64, 0, stream>>>(bsum_d, bsum_s, NB);
  k_scan3<<<NB, 256, 0, stream>>>(start_d, start_s, bsum_d, bsum_s,
                                  pos_d, pos_s, N);
  k_fill<<<eblk, 256, 0, stream>>>(ei, pos_d, pos_s, eidx_d, eidx_s, N, E);

  // edge MLPs
  edge_kernel<<<(E + 63) / 64, 256, 0, stream>>>(
      xbw, xsbw, ef, ei, (const u16*)Bfrag,
      (const float*)d_in[5], (const float*)d_in[6], (const float*)d_in[7],
      (const float*)d_in[9], (const float*)d_in[10], (const float*)d_in[11],
      pe, out_revw, N, E);

  // gather-aggregate -> bf16 message rows
  const int ablk = (N + 7) / 8;
  k_agg<0><<<ablk, 256, 0, stream>>>(x, ei, pe, out_revw, start_d, pos_d,
                                     eidx_d, (u16*)fwdmb, out_fwdw, N, E);
  k_agg<1><<<ablk, 256, 0, stream>>>(x, ei, pe, out_revw, start_s, pos_s,
                                     eidx_s, (u16*)revmb, out_fwdw, N, E);

  // fused node MLPs (reset + update + candidate + GRU)
  const int nblk = (N + 63) / 64;
  node_fused<<<nblk, 256, 0, stream>>>(
      x, xbw, fwdmb, revmb, NodeF,
      (const float*)d_in[13], (const float*)d_in[15],
      (const float*)d_in[17], (const float*)d_in[19],
      (const float*)d_in[21], (const float*)d_in[23],
      out_r, out_z, out_update, N);
}

// Round 5
// 1111.242 us; speedup vs baseline: 3.8044x; 1.0178x over previous
//
#include <hip/hip_runtime.h>
#include <math.h>

typedef unsigned short u16;
typedef unsigned int   u32;

#define HDIM 96
#define SDIM 48
#define FDIM 24
#define KA   312      // 2H + 2S + F
#define WATT 192
#define KG   288      // 3H

#define KT_A  10      // edge K-steps of 32 (K padded 312 -> 320)
#define KT_G  9       // node K-steps (288)
#define NS    296     // node LDS row stride in u16 (592 B = 37 uint4)

#define NFRAG (2 * KT_A * 12 * 64)   // edge W1 fragments (uint4 count) = 15360
#define W1F_Q (KT_G * 18 * 64)       // 10368 uint4 per node W1
#define W2F_Q (KT_G * 6 * 64)        //  3456 uint4 per node W2
#define NODEF_Q (3 * (W1F_Q + W2F_Q))

// prep_all block partition
#define PB_EDGE 60                   // NFRAG/256
#define PB_W1   41                   // ceil(10368/256)
#define PB_W2   14                   // ceil(3456/256)
#define PB_NODE (3 * (PB_W1 + PB_W2))  // 165

typedef __attribute__((ext_vector_type(8))) __bf16 bf16x8;
typedef __attribute__((ext_vector_type(4))) float  f32x4;

__device__ __forceinline__ u16 f2bf(float f) {
  u32 u = __float_as_uint(f);
  u = (u + 0x7FFFu + ((u >> 16) & 1u)) >> 16;   // RNE
  return (u16)u;
}
__device__ __forceinline__ float bf2f(u16 v) {
  return __uint_as_float((u32)v << 16);
}
__device__ __forceinline__ u32 pack2(float a, float b) {
  return (u32)f2bf(a) | ((u32)f2bf(b) << 16);
}
__device__ __forceinline__ f32x4 mfma_bf16(bf16x8 a, bf16x8 b, f32x4 c) {
  return __builtin_amdgcn_mfma_f32_16x16x32_bf16(a, b, c, 0, 0, 0);
}

// ===========================================================================
// prep_all: single launch doing all weight/activation conversion.
// blocks [0,60): edge W1 -> Bfrag (rev permutation folded, K pad 312->320)
// blocks [60,225): node W1/W2 x3 -> NodeF fragments
// blocks [225,...): x/xs fp32 -> bf16
// ===========================================================================
__global__ __launch_bounds__(256) void prep_all(
    const float* __restrict__ fW1, const float* __restrict__ rW1,
    uint4* __restrict__ Bfrag,
    const float* __restrict__ W1r, const float* __restrict__ W2r,
    const float* __restrict__ W1u, const float* __restrict__ W2u,
    const float* __restrict__ W1c, const float* __restrict__ W2c,
    uint4* __restrict__ NodeF,
    const float* __restrict__ x, const float* __restrict__ xs,
    u32* __restrict__ xb, u32* __restrict__ xsb, int N)
{
  int b = blockIdx.x;
  const int tid = threadIdx.x;

  if (b < PB_EDGE) {                       // ---- edge W1 fragments ----
    const int idx = b * 256 + tid;
    const int lane = idx & 63;
    const int frag = idx >> 6;
    const int nt   = frag % 12;
    const int rest = frag / 12;
    const int kt   = rest % KT_A;
    const int mlp  = rest / KT_A;
    const int q = lane >> 4, c = lane & 15;
    const int n  = nt * 16 + c;
    const int p0 = kt * 16 + q * 4;
    const float* W = mlp ? rW1 : fW1;
    u32 v[4];
#pragma unroll
    for (int w = 0; w < 4; ++w) {
      const int p = p0 + w;
      u32 val = 0u;
      if (p < 156) {
        int src = p;
        if (mlp) {
          if (src < 48)       src += 48;
          else if (src < 96)  src -= 48;
          else if (src < 120) src += 24;
          else if (src < 144) src -= 24;
        }
        const float2 wv = *(const float2*)(W + (size_t)n * KA + 2 * src);
        val = pack2(wv.x, wv.y);
      }
      v[w] = val;
    }
    Bfrag[idx] = make_uint4(v[0], v[1], v[2], v[3]);
    return;
  }
  b -= PB_EDGE;

  if (b < PB_NODE) {                       // ---- node weight fragments ----
    const int mlp = b / (PB_W1 + PB_W2);
    const int lb  = b % (PB_W1 + PB_W2);
    const float* W;
    uint4* o;
    int NT, idx;
    if (lb < PB_W1) {
      NT = 18; idx = lb * 256 + tid;
      W = (mlp == 0) ? W1r : (mlp == 1) ? W1u : W1c;
      o = NodeF + (size_t)mlp * (W1F_Q + W2F_Q);
    } else {
      NT = 6; idx = (lb - PB_W1) * 256 + tid;
      W = (mlp == 0) ? W2r : (mlp == 1) ? W2u : W2c;
      o = NodeF + (size_t)mlp * (W1F_Q + W2F_Q) + W1F_Q;
    }
    if (idx >= KT_G * NT * 64) return;
    const int lane = idx & 63;
    const int frag = idx >> 6;
    const int nt = frag % NT, kt = frag / NT;
    const int q = lane >> 4, c = lane & 15;
    const int n = nt * 16 + c;
    const int k0 = kt * 32 + q * 8;
    u32 v[4];
#pragma unroll
    for (int w = 0; w < 4; ++w) {
      const float2 wv = *(const float2*)(W + (size_t)n * KG + k0 + 2 * w);
      v[w] = pack2(wv.x, wv.y);
    }
    o[idx] = make_uint4(v[0], v[1], v[2], v[3]);
    return;
  }
  b -= PB_NODE;

  {                                        // ---- x / xs -> bf16 ----
    const int i = b * 256 + tid;
    const int nx = N * 48;
    if (i < nx) {
      const float2 v = ((const float2*)x)[i];
      xb[i] = pack2(v.x, v.y);
    } else if (i < nx + N * 24) {
      const float2 v = ((const float2*)xs)[i - nx];
      xsb[i - nx] = pack2(v.x, v.y);
    }
  }
}

// ===========================================================================
// Edge kernel v3: NO LDS A-tile. Every 8-bf16 A-fragment chunk lies in one
// source region (boundaries 48/96/120/144/156 pair-idx are 4-aligned), so
// lane (q,c) loads its fragment DIRECTLY from xb/xsb (ef: fp32+pack at
// kt=9). Both MLPs fused in one K-loop (A loaded once, 24 MFMA/kt, two
// accumulator sets). One __syncthreads in the whole kernel (epilogue red).
// ===========================================================================
__global__ __launch_bounds__(256, 2) void edge_kernel(
    const u32* __restrict__ xb, const u32* __restrict__ xsb,
    const float* __restrict__ ef, const int* __restrict__ ei,
    const u16* __restrict__ Bfrag,
    const float* __restrict__ fb1, const float* __restrict__ fW2,
    const float* __restrict__ fb2,
    const float* __restrict__ rb1, const float* __restrict__ rW2,
    const float* __restrict__ rb2,
    float* __restrict__ pe, float* __restrict__ out_revw, int N, int E)
{
  __shared__ float red[2][4][64];

  const int tid  = threadIdx.x;
  const int wave = tid >> 6, lane = tid & 63;
  const int q = lane >> 4, c = lane & 15;
  const int e0 = blockIdx.x * 64;

  // edge ids + endpoints for my 4 M-tiles (row c of each tile)
  int em[4], sm[4], dm[4];
#pragma unroll
  for (int m = 0; m < 4; ++m) {
    em[m] = min(e0 + m * 16 + c, E - 1);
    int s = ei[em[m]], d = ei[(size_t)E + em[m]];
    sm[m] = min(max(s, 0), N - 1);
    dm[m] = min(max(d, 0), N - 1);
  }

  const bf16x8* __restrict__ Bf = (const bf16x8*)Bfrag;

  f32x4 accF[4][3], accR[4][3];
#pragma unroll
  for (int m = 0; m < 4; ++m)
    for (int t = 0; t < 3; ++t) {
      accF[m][t] = (f32x4){0.f, 0.f, 0.f, 0.f};
      accR[m][t] = (f32x4){0.f, 0.f, 0.f, 0.f};
    }

#pragma unroll
  for (int kt = 0; kt < KT_A; ++kt) {
    const int p0 = kt * 16 + q * 4;          // u32-pair index of chunk start
    bf16x8 a[4];
#pragma unroll
    for (int m = 0; m < 4; ++m) {
      uint4 av;
      if (kt < 3) {
        av = *(const uint4*)(xb + (size_t)sm[m] * 48 + p0);
      } else if (kt < 6) {
        av = *(const uint4*)(xb + (size_t)dm[m] * 48 + (p0 - 48));
      } else if (kt == 6) {
        av = *(const uint4*)(xsb + (size_t)sm[m] * 24 + (p0 - 96));
      } else if (kt == 7) {
        const u32* p = (q < 2) ? xsb + (size_t)sm[m] * 24 + (p0 - 96)
                               : xsb + (size_t)dm[m] * 24 + (p0 - 120);
        av = *(const uint4*)p;
      } else if (kt == 8) {
        av = *(const uint4*)(xsb + (size_t)dm[m] * 24 + (p0 - 120));
      } else {
        if (q < 3) {
          const float* efp = ef + (size_t)em[m] * 24 + (p0 - 144) * 2;
          const float4 f0 = *(const float4*)efp;
          const float4 f1 = *(const float4*)(efp + 4);
          av = make_uint4(pack2(f0.x, f0.y), pack2(f0.z, f0.w),
                          pack2(f1.x, f1.y), pack2(f1.z, f1.w));
        } else {
          av = make_uint4(0u, 0u, 0u, 0u);   // K-pad (B is zero there too)
        }
      }
      a[m] = __builtin_bit_cast(bf16x8, av);
    }
#pragma unroll
    for (int t = 0; t < 3; ++t) {
      const bf16x8 bF = Bf[((kt * 12) + wave * 3 + t) * 64 + lane];
      const bf16x8 bR = Bf[(((KT_A + kt) * 12) + wave * 3 + t) * 64 + lane];
#pragma unroll
      for (int m = 0; m < 4; ++m) {
        accF[m][t] = mfma_bf16(a[m], bF, accF[m][t]);
        accR[m][t] = mfma_bf16(a[m], bR, accR[m][t]);
      }
    }
  }

  // ---- epilogue: bias + relu + dot(W2) for both MLPs, c-lane reduce ----
  float pf[4][4], pr[4][4];
#pragma unroll
  for (int m = 0; m < 4; ++m)
    for (int r = 0; r < 4; ++r) { pf[m][r] = 0.f; pr[m][r] = 0.f; }
#pragma unroll
  for (int t = 0; t < 3; ++t) {
    const int n = (wave * 3 + t) * 16 + c;
    const float fb = fb1[n], fw = fW2[n];
    const float rb = rb1[n], rw = rW2[n];
#pragma unroll
    for (int m = 0; m < 4; ++m)
      for (int r = 0; r < 4; ++r) {
        float hf = accF[m][t][r] + fb;
        hf = hf > 0.f ? hf : 0.f;
        pf[m][r] += hf * fw;
        float hr = accR[m][t][r] + rb;
        hr = hr > 0.f ? hr : 0.f;
        pr[m][r] += hr * rw;
      }
  }
  for (int off = 1; off <= 8; off <<= 1)
#pragma unroll
    for (int m = 0; m < 4; ++m)
      for (int r = 0; r < 4; ++r) {
        pf[m][r] += __shfl_xor(pf[m][r], off, 64);
        pr[m][r] += __shfl_xor(pr[m][r], off, 64);
      }

  if (c == 0) {
#pragma unroll
    for (int m = 0; m < 4; ++m)
      for (int r = 0; r < 4; ++r) {
        red[0][wave][m * 16 + q * 4 + r] = pf[m][r];
        red[1][wave][m * 16 + q * 4 + r] = pr[m][r];
      }
  }
  __syncthreads();

  if (tid < 64 && e0 + tid < E) {
    const int e = e0 + tid;
    float rawf = red[0][0][tid] + red[0][1][tid] + red[0][2][tid] + red[0][3][tid];
    rawf += fb2[0];
    const float lr = rawf > 0.f ? rawf : 0.01f * rawf;     // leaky_relu
    pe[e] = __expf(lr * 0.10206207261596575f);             // /sqrt(96)
    float rawr = red[1][0][tid] + red[1][1][tid] + red[1][2][tid] + red[1][3][tid];
    rawr += rb2[0];
    out_revw[e] = 1.f / (1.f + __expf(-rawr));
  }
}

// ===========================================================================
// CSR build.
// ===========================================================================
__global__ __launch_bounds__(256) void k_hist(
    const int* __restrict__ ei, int* __restrict__ deg_d,
    int* __restrict__ deg_s, int N, int E)
{
  const int e = blockIdx.x * 256 + threadIdx.x;
  if (e >= E) return;
  const int s = min(max(ei[e], 0), N - 1);
  const int d = min(max(ei[(size_t)E + e], 0), N - 1);
  atomicAdd(&deg_d[d], 1);
  atomicAdd(&deg_s[s], 1);
}

__global__ __launch_bounds__(256) void k_scan1(
    const int* __restrict__ deg_d, const int* __restrict__ deg_s,
    int* __restrict__ start_d, int* __restrict__ start_s,
    int* __restrict__ bsum_d, int* __restrict__ bsum_s, int N)
{
  __shared__ int sh[256];
  const int t = threadIdx.x, i = blockIdx.x * 256 + t;
  {
    const int v = (i < N) ? deg_d[i] : 0;
    sh[t] = v; __syncthreads();
    for (int off = 1; off < 256; off <<= 1) {
      const int u = (t >= off) ? sh[t - off] : 0;
      __syncthreads();
      sh[t] += u;
      __syncthreads();
    }
    if (i < N) start_d[i] = sh[t] - v;
    if (t == 255) bsum_d[blockIdx.x] = sh[255];
    __syncthreads();
  }
  {
    const int v = (i < N) ? deg_s[i] : 0;
    sh[t] = v; __syncthreads();
    for (int off = 1; off < 256; off <<= 1) {
      const int u = (t >= off) ? sh[t - off] : 0;
      __syncthreads();
      sh[t] += u;
      __syncthreads();
    }
    if (i < N) start_s[i] = sh[t] - v;
    if (t == 255) bsum_s[blockIdx.x] = sh[255];
  }
}

// scan2 folded in: each block sums bsum[0..blockIdx) itself (raw block sums).
__global__ __launch_bounds__(256) void k_scan3(
    int* __restrict__ start_d, int* __restrict__ start_s,
    const int* __restrict__ bsum_d, const int* __restrict__ bsum_s,
    int* __restrict__ pos_d, int* __restrict__ pos_s, int N)
{
  __shared__ int offs[2];
  const int t = threadIdx.x;
  if (t < 2) {
    const int* bs = t ? bsum_s : bsum_d;
    int r = 0;
    for (int bb = 0; bb < (int)blockIdx.x; ++bb) r += bs[bb];
    offs[t] = r;
  }
  __syncthreads();
  const int i = blockIdx.x * 256 + t;
  if (i >= N) return;
  const int vd = start_d[i] + offs[0]; start_d[i] = vd; pos_d[i] = vd;
  const int vs = start_s[i] + offs[1]; start_s[i] = vs; pos_s[i] = vs;
}

__global__ __launch_bounds__(256) void k_fill(
    const int* __restrict__ ei, int* __restrict__ pos_d,
    int* __restrict__ pos_s, int* __restrict__ eidx_d,
    int* __restrict__ eidx_s, int N, int E)
{
  const int e = blockIdx.x * 256 + threadIdx.x;
  if (e >= E) return;
  const int s = min(max(ei[e], 0), N - 1);
  const int d = min(max(ei[(size_t)E + e], 0), N - 1);
  eidx_d[atomicAdd(&pos_d[d], 1)] = e;
  eidx_s[atomicAdd(&pos_s[s], 1)] = e;
}

// ===========================================================================
// Gather-aggregate, both directions in one launch (block range split).
// ===========================================================================
__global__ __launch_bounds__(256) void k_agg_all(
    const float* __restrict__ x, const int* __restrict__ ei,
    const float* __restrict__ pe, const float* __restrict__ revw,
    const int* __restrict__ start_d, const int* __restrict__ end_d,
    const int* __restrict__ eidx_d,
    const int* __restrict__ start_s, const int* __restrict__ end_s,
    const int* __restrict__ eidx_s,
    u16* __restrict__ fwdm, u16* __restrict__ revm,
    float* __restrict__ out_fwdw, int N, int E, int ablk)
{
  int b = blockIdx.x;
  const int dir = (b >= ablk) ? 1 : 0;
  if (dir) b -= ablk;
  const int g = threadIdx.x >> 5;
  const int l = threadIdx.x & 31;
  const int n = b * 8 + g;
  if (n >= N) return;

  const int* start = dir ? start_s : start_d;
  const int* endp  = dir ? end_s   : end_d;
  const int* eidx  = dir ? eidx_s  : eidx_d;
  const int beg = start[n], end = endp[n];

  float inv = 1.f;
  if (dir == 0) {
    float sum = 0.f;
    for (int i = beg + l; i < end; i += 32) sum += pe[eidx[i]];
    for (int off = 16; off; off >>= 1) sum += __shfl_xor(sum, off, 32);
    inv = 1.f / (sum + 1e-9f);
    for (int i = beg + l; i < end; i += 32) {
      const int e = eidx[i];
      out_fwdw[e] = pe[e] * inv;
    }
  }

  float a0 = 0.f, a1 = 0.f, a2 = 0.f;
  for (int i = beg; i < end; ++i) {
    const int e = eidx[i];
    const float w = (dir == 0) ? pe[e] * inv : revw[e];
    const int o = (dir == 0) ? min(max(ei[e], 0), N - 1)
                             : min(max(ei[(size_t)E + e], 0), N - 1);
    const float* xr = x + (size_t)o * 96;
    a0 += w * xr[l];
    a1 += w * xr[l + 32];
    a2 += w * xr[l + 64];
  }
  u16* orow = (dir ? revm : fwdm) + (size_t)n * 96;
  orow[l] = f2bf(a0); orow[l + 32] = f2bf(a1); orow[l + 64] = f2bf(a2);
}

// ===========================================================================
// Fused node kernel: 64 nodes/block (4 M-tiles), spill-proof gather
// (per-branch straight-line load->store). Reg-resident weight fragments.
// ===========================================================================
__device__ __forceinline__ void node_mlp(
    const u16* __restrict__ Alds, u16* __restrict__ Hlds,
    const bf16x8* __restrict__ W1f, const bf16x8* __restrict__ W2f,
    const float* __restrict__ b1,
    int wave, int lane, int q, int c, int ntc, int ntc2,
    f32x4 (&acc2)[4][2])
{
  f32x4 acc[4][5];
#pragma unroll
  for (int m = 0; m < 4; ++m)
    for (int t = 0; t < 5; ++t) acc[m][t] = (f32x4){0.f, 0.f, 0.f, 0.f};

#pragma unroll
  for (int kt = 0; kt < KT_G; ++kt) {
    bf16x8 a[4];
#pragma unroll
    for (int m = 0; m < 4; ++m)
      a[m] = *(const bf16x8*)&Alds[(m * 16 + c) * NS + kt * 32 + q * 8];
#pragma unroll
    for (int t = 0; t < 5; ++t) {
      if (t < ntc) {
        const int nt = wave + 4 * t;
        const bf16x8 b = W1f[(kt * 18 + nt) * 64 + lane];
#pragma unroll
        for (int m = 0; m < 4; ++m)
          acc[m][t] = mfma_bf16(a[m], b, acc[m][t]);
      }
    }
  }

  __syncthreads();                       // prior Hlds readers done
#pragma unroll
  for (int t = 0; t < 5; ++t) {
    if (t < ntc) {
      const int n = (wave + 4 * t) * 16 + c;
      const float b1f = b1[n];
#pragma unroll
      for (int m = 0; m < 4; ++m)
        for (int r = 0; r < 4; ++r) {
          float h = acc[m][t][r] + b1f;
          h = h > 0.f ? h : 0.f;
          Hlds[(m * 16 + q * 4 + r) * NS + n] = f2bf(h);
        }
    }
  }
  __syncthreads();                       // H complete

#pragma unroll
  for (int m = 0; m < 4; ++m)
    for (int t = 0; t < 2; ++t) acc2[m][t] = (f32x4){0.f, 0.f, 0.f, 0.f};
#pragma unroll
  for (int kt = 0; kt < KT_G; ++kt) {
    bf16x8 a[4];
#pragma unroll
    for (int m = 0; m < 4; ++m)
      a[m] = *(const bf16x8*)&Hlds[(m * 16 + c) * NS + kt * 32 + q * 8];
#pragma unroll
    for (int t = 0; t < 2; ++t) {
      if (t < ntc2) {
        const int nt = wave + 4 * t;
        const bf16x8 b = W2f[(kt * 6 + nt) * 64 + lane];
#pragma unroll
        for (int m = 0; m < 4; ++m)
          acc2[m][t] = mfma_bf16(a[m], b, acc2[m][t]);
      }
    }
  }
}

__global__ __launch_bounds__(256, 2) void node_fused(
    const float* __restrict__ x, const u32* __restrict__ xb,
    const u32* __restrict__ fwdmb, const u32* __restrict__ revmb,
    const uint4* __restrict__ NodeF,
    const float* __restrict__ b1r, const float* __restrict__ b2r,
    const float* __restrict__ b1u, const float* __restrict__ b2u,
    const float* __restrict__ b1c, const float* __restrict__ b2c,
    float* __restrict__ out_r, float* __restrict__ out_z,
    float* __restrict__ out_upd, int N)
{
  __shared__ __align__(16) u16 Alds[64 * NS];   // 37,888 B
  __shared__ __align__(16) u16 Hlds[64 * NS];   // 37,888 B

  const int tid = threadIdx.x;
  const int wave = tid >> 6, lane = tid & 63;
  const int q = lane >> 4, c = lane & 15;
  const int n0 = blockIdx.x * 64;
  const int ntc  = (wave < 2) ? 5 : 4;
  const int ntc2 = (wave < 2) ? 2 : 1;

  // ---- gather A: spill-proof per-branch bursts (u4 map: x|f|r 12 each) ---
  {
    const int nl = tid >> 2, sub = tid & 3;
    const int node = min(n0 + nl, N - 1);
    const uint4* xr = (const uint4*)(xb    + (size_t)node * 48);
    const uint4* fr = (const uint4*)(fwdmb + (size_t)node * 48);
    const uint4* rr = (const uint4*)(revmb + (size_t)node * 48);
    uint4* Arow = (uint4*)&Alds[nl * NS];       // 37 u4/row
    if (sub == 0) {
      uint4 t0 = xr[0], t1 = xr[1], t2 = xr[2], t3 = xr[3], t4 = xr[4],
            t5 = xr[5], t6 = xr[6], t7 = xr[7], t8 = xr[8];
      Arow[0] = t0; Arow[1] = t1; Arow[2] = t2; Arow[3] = t3; Arow[4] = t4;
      Arow[5] = t5; Arow[6] = t6; Arow[7] = t7; Arow[8] = t8;
    } else if (sub == 1) {
      uint4 t0 = xr[9], t1 = xr[10], t2 = xr[11], t3 = fr[0], t4 = fr[1],
            t5 = fr[2], t6 = fr[3], t7 = fr[4], t8 = fr[5];
      Arow[9] = t0; Arow[10] = t1; Arow[11] = t2; Arow[12] = t3;
      Arow[13] = t4; Arow[14] = t5; Arow[15] = t6; Arow[16] = t7;
      Arow[17] = t8;
    } else if (sub == 2) {
      uint4 t0 = fr[6], t1 = fr[7], t2 = fr[8], t3 = fr[9], t4 = fr[10],
            t5 = fr[11], t6 = rr[0], t7 = rr[1], t8 = rr[2];
      Arow[18] = t0; Arow[19] = t1; Arow[20] = t2; Arow[21] = t3;
      Arow[22] = t4; Arow[23] = t5; Arow[24] = t6; Arow[25] = t7;
      Arow[26] = t8;
    } else {
      uint4 t0 = rr[3], t1 = rr[4], t2 = rr[5], t3 = rr[6], t4 = rr[7],
            t5 = rr[8], t6 = rr[9], t7 = rr[10], t8 = rr[11];
      Arow[27] = t0; Arow[28] = t1; Arow[29] = t2; Arow[30] = t3;
      Arow[31] = t4; Arow[32] = t5; Arow[33] = t6; Arow[34] = t7;
      Arow[35] = t8;
    }
  }
  __syncthreads();

  const bf16x8* W1fr = (const bf16x8*)(NodeF);
  const bf16x8* W2fr = (const bf16x8*)(NodeF + W1F_Q);
  const bf16x8* W1fu = (const bf16x8*)(NodeF + W1F_Q + W2F_Q);
  const bf16x8* W2fu = (const bf16x8*)(NodeF + 2 * W1F_Q + W2F_Q);
  const bf16x8* W1fc = (const bf16x8*)(NodeF + 2 * (W1F_Q + W2F_Q));
  const bf16x8* W2fc = (const bf16x8*)(NodeF + 3 * W1F_Q + 2 * W2F_Q);

  f32x4 acc2[4][2];

  // ---- reset gate ----
  node_mlp(Alds, Hlds, W1fr, W2fr, b1r, wave, lane, q, c, ntc, ntc2, acc2);
  float r_reg[2][4][4];
#pragma unroll
  for (int t = 0; t < 2; ++t) {
    if (t < ntc2) {
      const int n2 = (wave + 4 * t) * 16 + c;
      const float b2f = b2r[n2];
#pragma unroll
      for (int m = 0; m < 4; ++m)
        for (int r = 0; r < 4; ++r) {
          const float v = acc2[m][t][r] + b2f;
          const float rv = 1.f / (1.f + __expf(-v));
          r_reg[t][m][r] = rv;
          const int node = n0 + m * 16 + q * 4 + r;
          if (node < N) out_r[(size_t)node * HDIM + n2] = rv;
        }
    }
  }

  // ---- update gate ----
  node_mlp(Alds, Hlds, W1fu, W2fu, b1u, wave, lane, q, c, ntc, ntc2, acc2);
  float z_reg[2][4][4];
#pragma unroll
  for (int t = 0; t < 2; ++t) {
    if (t < ntc2) {
      const int n2 = (wave + 4 * t) * 16 + c;
      const float b2f = b2u[n2];
#pragma unroll
      for (int m = 0; m < 4; ++m)
        for (int r = 0; r < 4; ++r) {
          const float v = acc2[m][t][r] + b2f;
          const float zv = 1.f / (1.f + __expf(-v));
          z_reg[t][m][r] = zv;
          const int node = n0 + m * 16 + q * 4 + r;
          if (node < N) out_z[(size_t)node * HDIM + n2] = zv;
        }
    }
  }

  // ---- apply r to the x-columns of A in place (disjoint coverage) ----
#pragma unroll
  for (int t = 0; t < 2; ++t) {
    if (t < ntc2) {
      const int n2 = (wave + 4 * t) * 16 + c;
#pragma unroll
      for (int m = 0; m < 4; ++m)
        for (int r = 0; r < 4; ++r) {
          const int row = m * 16 + q * 4 + r;
          const int idx = row * NS + n2;
          Alds[idx] = f2bf(bf2f(Alds[idx]) * r_reg[t][m][r]);
        }
    }
  }
  __syncthreads();

  // ---- candidate + GRU update ----
  node_mlp(Alds, Hlds, W1fc, W2fc, b1c, wave, lane, q, c, ntc, ntc2, acc2);
#pragma unroll
  for (int t = 0; t < 2; ++t) {
    if (t < ntc2) {
      const int n2 = (wave + 4 * t) * 16 + c;
      const float b2f = b2c[n2];
#pragma unroll
      for (int m = 0; m < 4; ++m)
        for (int r = 0; r < 4; ++r) {
          const int node = n0 + m * 16 + q * 4 + r;
          if (node < N) {
            const float v = acc2[m][t][r] + b2f;
            const float ct = tanhf(v);
            const float z = z_reg[t][m][r];
            const float xv = x[(size_t)node * HDIM + n2];
            out_upd[(size_t)node * HDIM + n2] = (1.f - z) * xv + z * ct;
          }
        }
    }
  }
}

__global__ void sentinel_kernel(float* out, int n, float val) {
  const int i = blockIdx.x * 256 + threadIdx.x;
  if (i < n) out[i] = val;
}

// ---------------------------------------------------------------------------
extern "C" void kernel_launch(void* const* d_in, const int* in_sizes, int n_in,
                              void* d_out, int out_size, void* d_ws, size_t ws_size,
                              hipStream_t stream) {
  const float* x  = (const float*)d_in[0];
  const float* xs = (const float*)d_in[1];
  const float* ef = (const float*)d_in[2];
  const int*   ei = (const int*)d_in[3];

  const int N = in_sizes[0] / HDIM;
  const int E = in_sizes[3] / 2;

  float* out = (float*)d_out;

  const int NB = (N + 255) / 256;      // scan blocks (<=1024 supported)

  const bool sizes_ok =
      n_in == 24 && NB <= 1024 &&
      in_sizes[0] == N * HDIM && in_sizes[1] == N * SDIM &&
      in_sizes[2] == E * FDIM && in_sizes[3] == 2 * E &&
      in_sizes[4] == WATT * KA && in_sizes[5] == WATT &&
      in_sizes[6] == WATT && in_sizes[7] == 1 &&
      in_sizes[12] == KG * KG && in_sizes[13] == KG &&
      in_sizes[14] == HDIM * KG && in_sizes[15] == HDIM &&
      out_size == 3 * N * HDIM + 2 * E;
  if (!sizes_ok) {
    sentinel_kernel<<<(out_size + 255) / 256, 256, 0, stream>>>(out, out_size, 777.0f);
    return;
  }

  // ws layout (u32 units) — unchanged from R4
  const size_t eA = ((size_t)E + 3) & ~(size_t)3;
  const size_t needed =
      (eA + (size_t)NFRAG * 4 + (size_t)NODEF_Q * 4 +
       (size_t)N * 48 + (size_t)N * 24 + 2 * (size_t)N * 48 +
       6 * (size_t)N + 2048 + 2 * (size_t)E) * 4;
  if (ws_size < needed) {
    sentinel_kernel<<<(out_size + 255) / 256, 256, 0, stream>>>(out, out_size, 12345.0f);
    return;
  }
  float* pe    = (float*)d_ws;
  uint4* Bfrag = (uint4*)((u32*)d_ws + eA);
  uint4* NodeF = Bfrag + NFRAG;
  u32*   xbw   = (u32*)(NodeF + NODEF_Q);
  u32*   xsbw  = xbw + (size_t)N * 48;
  u32*   fwdmb = xsbw + (size_t)N * 24;
  u32*   revmb = fwdmb + (size_t)N * 48;
  int* deg_d   = (int*)(revmb + (size_t)N * 48);
  int* deg_s   = deg_d + N;
  int* start_d = deg_s + N;
  int* start_s = start_d + N;
  int* pos_d   = start_s + N;
  int* pos_s   = pos_d + N;
  int* bsum_d  = pos_s + N;
  int* bsum_s  = bsum_d + 1024;
  int* eidx_d  = bsum_s + 1024;
  int* eidx_s  = eidx_d + E;

  float* out_update = out;                         // [N,96]
  float* out_fwdw   = out + (size_t)N * HDIM;      // [E]
  float* out_revw   = out_fwdw + E;                // [E]
  float* out_z      = out_revw + E;                // [N,96]
  float* out_r      = out_z + (size_t)N * HDIM;    // [N,96]

  (void)hipMemsetAsync(deg_d, 0, 2 * (size_t)N * sizeof(int), stream);

  // single merged prep launch (edge W1, node W1/W2 x3, x/xs -> bf16)
  const int prep_blocks = PB_EDGE + PB_NODE + (N * 72 + 255) / 256;
  prep_all<<<prep_blocks, 256, 0, stream>>>(
      (const float*)d_in[4], (const float*)d_in[8], Bfrag,
      (const float*)d_in[12], (const float*)d_in[14],
      (const float*)d_in[16], (const float*)d_in[18],
      (const float*)d_in[20], (const float*)d_in[22], NodeF,
      x, xs, xbw, xsbw, N);

  // CSR build
  const int eblk = (E + 255) / 256;
  k_hist<<<eblk, 256, 0, stream>>>(ei, deg_d, deg_s, N, E);
  k_scan1<<<NB, 256, 0, stream>>>(deg_d, deg_s, start_d, start_s,
                                  bsum_d, bsum_s, N);
  k_scan3<<<NB, 256, 0, stream>>>(start_d, start_s, bsum_d, bsum_s,
                                  pos_d, pos_s, N);
  k_fill<<<eblk, 256, 0, stream>>>(ei, pos_d, pos_s, eidx_d, eidx_s, N, E);

  // edge MLPs (direct-global A, fused fwd+rev)
  edge_kernel<<<(E + 63) / 64, 256, 0, stream>>>(
      xbw, xsbw, ef, ei, (const u16*)Bfrag,
      (const float*)d_in[5], (const float*)d_in[6], (const float*)d_in[7],
      (const float*)d_in[9], (const float*)d_in[10], (const float*)d_in[11],
      pe, out_revw, N, E);

  // gather-aggregate (both directions, one launch)
  const int ablk = (N + 7) / 8;
  k_agg_all<<<2 * ablk, 256, 0, stream>>>(
      x, ei, pe, out_revw,
      start_d, pos_d, eidx_d, start_s, pos_s, eidx_s,
      (u16*)fwdmb, (u16*)revmb, out_fwdw, N, E, ablk);

  // fused node MLPs
  const int nblk = (N + 63) / 64;
  node_fused<<<nblk, 256, 0, stream>>>(
      x, xbw, fwdmb, revmb, NodeF,
      (const float*)d_in[13], (const float*)d_in[15],
      (const float*)d_in[17], (const float*)d_in[19],
      (const float*)d_in[21], (const float*)d_in[23],
      out_r, out_z, out_update, N);
}